// Round 1
// baseline (727.407 us; speedup 1.0000x reference)
//
#include <hip/hip_runtime.h>
#include <hip/hip_bf16.h>

// Problem constants
#define B_  2
#define N_  1024
#define D_  256
#define E_  64
#define H_  8
#define HS_ 64
#define FF_ 1024
#define R_  (B_*N_)   // 2048 rows (b,n)

typedef short bf8 __attribute__((ext_vector_type(8)));   // 8 bf16 (bit pattern) = 4 VGPRs
typedef float f4  __attribute__((ext_vector_type(4)));

static __device__ __forceinline__ ushort f2b(float f) {
  __hip_bfloat16 h = __float2bfloat16(f);
  return *reinterpret_cast<ushort*>(&h);
}

// ---------------- pack / convert kernels ----------------

__global__ void k_cvt(const float* __restrict__ src, ushort* __restrict__ dst, int n) {
  int i = blockIdx.x * 256 + threadIdx.x;
  if (i < n) dst[i] = f2b(src[i]);
}

// Wqkv_packed [256 x 1536]: cols 0..511 = q (h,o) scaled 1/8, 512..1023 = k-node, 1024..1535 = v
__global__ void k_pack_wqkv(const float* __restrict__ Wq, const float* __restrict__ Wk,
                            const float* __restrict__ Wv, ushort* __restrict__ out) {
  int idx = blockIdx.x * 256 + threadIdx.x;   // 256*1536
  if (idx >= 256 * 1536) return;
  int i = idx / 1536, c = idx % 1536;
  int mat = c >> 9, h = (c >> 6) & 7, o = c & 63;
  float v;
  if (mat == 0)      v = Wq[(h * 256 + i) * 64 + o] * 0.125f;   // q scaled by 1/sqrt(HS)
  else if (mat == 1) v = Wk[(h * 320 + i) * 64 + o];            // Wk is [H][320][64]
  else               v = Wv[(h * 256 + i) * 64 + o];
  out[idx] = f2b(v);
}

// Block-diagonal WkE [512 x 512]: row=(h*64+o), col=(h2*64+e); nonzero iff h2==h -> WkE[h][e][o]
__global__ void k_pack_wke(const float* __restrict__ Wk, ushort* __restrict__ out) {
  int idx = blockIdx.x * 256 + threadIdx.x;   // 512*512
  if (idx >= 512 * 512) return;
  int row = idx >> 9, c = idx & 511;
  int h = row >> 6, o = row & 63;
  int h2 = c >> 6, e = c & 63;
  float v = (h2 == h) ? Wk[(h * 320 + 256 + e) * 64 + o] : 0.0f;
  out[idx] = f2b(v);
}

// knT[b][h][o][m] <- qkv[(b*1024+m)*1536 + 512 + h*64 + o]
__global__ void k_knT(const ushort* __restrict__ qkv, ushort* __restrict__ knt) {
  int idx = blockIdx.x * 256 + threadIdx.x;   // 16*64*1024 = 1048576
  if (idx >= 16 * 64 * 1024) return;
  int m = idx & 1023;
  int rest = idx >> 10;
  int o = rest & 63;
  int bh = rest >> 6;
  int b = bh >> 3, h = bh & 7;
  knt[idx] = qkv[(size_t)(b * 1024 + m) * 1536 + 512 + h * 64 + o];
}

// ---------------- generic bf16 MFMA GEMM ----------------
// C[M x N] = A[M x K] @ B[K x N]  (A,B bf16 row-major with strides; C fp32 or bf16)
// EPI: 0=none, 1=C+=, 2=+bias, 3=+bias,relu   OBF: 1 -> write bf16
// Batched via blockIdx.z: offset = (z>>3)*s1 + (z&7)*s2  (element offsets)
template<int EPI, int OBF>
__global__ void k_gemm(const ushort* __restrict__ A, const ushort* __restrict__ Bm,
                       void* __restrict__ Cv, const float* __restrict__ bias,
                       int M, int N, int K, int lda, int ldb, int ldc,
                       long long as1, long long as2, long long bs1, long long bs2,
                       long long cs1, long long cs2) {
  int z = blockIdx.z;
  const ushort* Ab = A + (size_t)((z >> 3) * as1 + (z & 7) * as2);
  const ushort* Bb = Bm + (size_t)((z >> 3) * bs1 + (z & 7) * bs2);
  size_t coff = (size_t)((z >> 3) * cs1 + (z & 7) * cs2);
  int r0 = blockIdx.x * 64, c0 = blockIdx.y * 64;

  __shared__ ushort As[64][40];   // +8 pad: 80B rows -> 2-way max on b128 frag reads
  __shared__ ushort Bs[32][72];   // +8 pad

  int tid = threadIdx.x;
  int lane = tid & 63, w = tid >> 6;
  int wm = w >> 1, wn = w & 1;            // wave -> 32x32 quadrant
  int kg = lane >> 4, lr = lane & 15;

  f4 acc[2][2] = {};

  for (int k0 = 0; k0 < K; k0 += 32) {
    __syncthreads();
    { // stage A tile 64x32 (one 16B load per thread)
      int row = tid >> 2, ch = tid & 3;
      *(int4*)&As[row][ch * 8] = *(const int4*)(Ab + (size_t)(r0 + row) * lda + k0 + ch * 8);
    }
    { // stage B tile 32x64
      int kk = tid >> 3, ch = tid & 7;
      *(int4*)&Bs[kk][ch * 8] = *(const int4*)(Bb + (size_t)(k0 + kk) * ldb + c0 + ch * 8);
    }
    __syncthreads();

    bf8 bfr[2];
    #pragma unroll
    for (int cb = 0; cb < 2; ++cb) {
      #pragma unroll
      for (int j = 0; j < 8; ++j)
        bfr[cb][j] = (short)Bs[kg * 8 + j][wn * 32 + cb * 16 + lr];  // B: col=l&15, k=8*kg+j
    }
    #pragma unroll
    for (int rb = 0; rb < 2; ++rb) {
      bf8 af = *(const bf8*)&As[wm * 32 + rb * 16 + lr][kg * 8];     // A: row=l&15, k=8*kg+j
      #pragma unroll
      for (int cb = 0; cb < 2; ++cb)
        acc[rb][cb] = __builtin_amdgcn_mfma_f32_16x16x32_bf16(af, bfr[cb], acc[rb][cb], 0, 0, 0);
    }
  }

  float* Cf = (float*)Cv;
  ushort* Cb = (ushort*)Cv;
  #pragma unroll
  for (int rb = 0; rb < 2; ++rb) {
    #pragma unroll
    for (int cb = 0; cb < 2; ++cb) {
      #pragma unroll
      for (int rr = 0; rr < 4; ++rr) {
        int row = r0 + wm * 32 + rb * 16 + kg * 4 + rr;   // D: col=l&15, row=4*kg+reg
        int col = c0 + wn * 32 + cb * 16 + lr;
        size_t ci = coff + (size_t)row * ldc + col;
        float v = acc[rb][cb][rr];
        if (EPI == 1) v += Cf[ci];
        if (EPI >= 2) v += bias[col];
        if (EPI == 3) v = fmaxf(v, 0.0f);
        if (OBF) Cb[ci] = f2b(v); else Cf[ci] = v;
      }
    }
  }
}

// ---------------- edge-conditioned logits (the 512 MiB streamer) ----------------
// logits[b][h][n][m] = sum_e qe[b,n,h,e] * edge[b,n,m,e]   (WRITE, node part added later)
// One block per (b,n); thread owns m = tid + 256*j, j=0..3; qe register-cached per e-chunk.
__global__ void k_edge(const float* __restrict__ edge, const float* __restrict__ qe,
                       float* __restrict__ logits) {
  int bid = blockIdx.x;            // b*1024 + n
  int b = bid >> 10, n = bid & 1023;
  int tid = threadIdx.x;

  __shared__ float qes[512];       // qe row: [h*64 + e]
  { float2 t = reinterpret_cast<const float2*>(qe + (size_t)bid * 512)[tid];
    qes[tid * 2] = t.x; qes[tid * 2 + 1] = t.y; }
  __syncthreads();

  float acc[4][8] = {};
  const float* eb = edge + (size_t)bid * 65536;   // 1024*64 floats

  #pragma unroll 1
  for (int ec = 0; ec < 8; ++ec) {       // e-chunks of 8
    float qv[8][8];
    #pragma unroll
    for (int h = 0; h < 8; ++h) {
      float4 a = *(const float4*)&qes[h * 64 + ec * 8];
      float4 c = *(const float4*)&qes[h * 64 + ec * 8 + 4];
      qv[h][0] = a.x; qv[h][1] = a.y; qv[h][2] = a.z; qv[h][3] = a.w;
      qv[h][4] = c.x; qv[h][5] = c.y; qv[h][6] = c.z; qv[h][7] = c.w;
    }
    #pragma unroll
    for (int j = 0; j < 4; ++j) {
      const float* ep = eb + (size_t)(tid + 256 * j) * 64 + ec * 8;
      float4 e0 = *(const float4*)ep;
      float4 e1 = *(const float4*)(ep + 4);
      #pragma unroll
      for (int h = 0; h < 8; ++h) {
        acc[j][h] += e0.x * qv[h][0] + e0.y * qv[h][1] + e0.z * qv[h][2] + e0.w * qv[h][3]
                   + e1.x * qv[h][4] + e1.y * qv[h][5] + e1.z * qv[h][6] + e1.w * qv[h][7];
      }
    }
  }

  #pragma unroll
  for (int h = 0; h < 8; ++h) {
    size_t base = ((size_t)(b * 8 + h) * 1024 + n) * 1024;
    #pragma unroll
    for (int j = 0; j < 4; ++j)
      logits[base + tid + 256 * j] = acc[j][h];
  }
}

// ---------------- softmax: fp32 logits row -> bf16 attn row ----------------
__global__ void k_softmax(const float* __restrict__ logits, ushort* __restrict__ attn) {
  int z = blockIdx.x;              // (b*8+h)*1024 + n, 16384 rows
  int tid = threadIdx.x;
  const float4* in = reinterpret_cast<const float4*>(logits + (size_t)z * 1024);
  float4 v = in[tid];
  __shared__ float red[4];

  float mx = fmaxf(fmaxf(v.x, v.y), fmaxf(v.z, v.w));
  for (int off = 32; off; off >>= 1) mx = fmaxf(mx, __shfl_xor(mx, off));
  if ((tid & 63) == 0) red[tid >> 6] = mx;
  __syncthreads();
  mx = fmaxf(fmaxf(red[0], red[1]), fmaxf(red[2], red[3]));
  __syncthreads();

  float e0 = __expf(v.x - mx), e1 = __expf(v.y - mx), e2 = __expf(v.z - mx), e3 = __expf(v.w - mx);
  float s = e0 + e1 + e2 + e3;
  for (int off = 32; off; off >>= 1) s += __shfl_xor(s, off);
  if ((tid & 63) == 0) red[tid >> 6] = s;
  __syncthreads();
  s = red[0] + red[1] + red[2] + red[3];

  float inv = 1.0f / s;
  uint2 outp;
  outp.x = (uint)f2b(e0 * inv) | ((uint)f2b(e1 * inv) << 16);
  outp.y = (uint)f2b(e2 * inv) | ((uint)f2b(e3 * inv) << 16);
  reinterpret_cast<uint2*>(attn + (size_t)z * 1024)[tid] = outp;
}

// ---------------- residual + layernorm (D=256, one block per row) ----------------
__global__ void k_ln(const float* __restrict__ a, const float* __restrict__ bb,
                     const float* __restrict__ g, const float* __restrict__ be,
                     float* __restrict__ of, ushort* __restrict__ ob) {
  int r = blockIdx.x, i = threadIdx.x;
  float t = a[(size_t)r * 256 + i] + bb[(size_t)r * 256 + i];
  __shared__ float red[4];

  float s = t;
  for (int off = 32; off; off >>= 1) s += __shfl_xor(s, off);
  if ((i & 63) == 0) red[i >> 6] = s;
  __syncthreads();
  float mean = (red[0] + red[1] + red[2] + red[3]) * (1.0f / 256.0f);
  __syncthreads();

  float d = t - mean;
  float q = d * d;
  for (int off = 32; off; off >>= 1) q += __shfl_xor(q, off);
  if ((i & 63) == 0) red[i >> 6] = q;
  __syncthreads();
  float var = (red[0] + red[1] + red[2] + red[3]) * (1.0f / 256.0f);

  float y = d * rsqrtf(var + 1e-6f) * g[i] + be[i];
  of[(size_t)r * 256 + i] = y;
  if (ob) ob[(size_t)r * 256 + i] = f2b(y);
}

// ---------------- launch ----------------

extern "C" void kernel_launch(void* const* d_in, const int* in_sizes, int n_in,
                              void* d_out, int out_size, void* d_ws, size_t ws_size,
                              hipStream_t stream) {
  (void)in_sizes; (void)n_in; (void)out_size; (void)ws_size;
  const float* node = (const float*)d_in[0];
  const float* edge = (const float*)d_in[1];
  const float* Wq   = (const float*)d_in[2];
  const float* Wk   = (const float*)d_in[3];
  const float* Wv   = (const float*)d_in[4];
  const float* Wp   = (const float*)d_in[5];
  const float* bp   = (const float*)d_in[6];
  const float* g1   = (const float*)d_in[7];
  const float* be1  = (const float*)d_in[8];
  const float* W1   = (const float*)d_in[9];
  const float* b1   = (const float*)d_in[10];
  const float* W2   = (const float*)d_in[11];
  const float* b2   = (const float*)d_in[12];
  const float* g2   = (const float*)d_in[13];
  const float* be2  = (const float*)d_in[14];
  float* out = (float*)d_out;

  char* ws = (char*)d_ws;
  size_t off = 0;
  auto alloc = [&](size_t bytes) -> char* {
    char* p = ws + off;
    off = (off + bytes + 255) & ~(size_t)255;
    return p;
  };
  ushort* node_bf = (ushort*)alloc((size_t)R_ * D_ * 2);          // 1 MiB
  ushort* wqkv    = (ushort*)alloc((size_t)256 * 1536 * 2);       // 768 KiB
  ushort* wke     = (ushort*)alloc((size_t)512 * 512 * 2);        // 512 KiB
  ushort* wp      = (ushort*)alloc((size_t)512 * 256 * 2);        // 256 KiB
  ushort* w1      = (ushort*)alloc((size_t)256 * 1024 * 2);       // 512 KiB
  ushort* w2      = (ushort*)alloc((size_t)1024 * 256 * 2);       // 512 KiB
  ushort* qkv     = (ushort*)alloc((size_t)R_ * 1536 * 2);        // 6 MiB
  float*  qe      = (float*) alloc((size_t)R_ * 512 * 4);         // 4 MiB
  ushort* knt     = (ushort*)alloc((size_t)16 * 64 * 1024 * 2);   // 2 MiB
  float*  logits  = (float*) alloc((size_t)16 * 1024 * 1024 * 4); // 64 MiB
  ushort* attn    = (ushort*)alloc((size_t)16 * 1024 * 1024 * 2); // 32 MiB
  ushort* mo      = (ushort*)alloc((size_t)R_ * 512 * 2);         // 2 MiB
  float*  mha     = (float*) alloc((size_t)R_ * 256 * 4);         // 2 MiB
  float*  xf      = (float*) alloc((size_t)R_ * 256 * 4);         // 2 MiB
  ushort* xb      = (ushort*)alloc((size_t)R_ * 256 * 2);         // 1 MiB
  ushort* hb      = (ushort*)alloc((size_t)R_ * 1024 * 2);        // 4 MiB
  float*  ff      = (float*) alloc((size_t)R_ * 256 * 4);         // 2 MiB

  // --- pack / convert ---
  k_cvt<<<dim3((R_ * D_ + 255) / 256), dim3(256), 0, stream>>>(node, node_bf, R_ * D_);
  k_cvt<<<dim3((512 * 256 + 255) / 256), dim3(256), 0, stream>>>(Wp, wp, 512 * 256);
  k_cvt<<<dim3((256 * 1024 + 255) / 256), dim3(256), 0, stream>>>(W1, w1, 256 * 1024);
  k_cvt<<<dim3((1024 * 256 + 255) / 256), dim3(256), 0, stream>>>(W2, w2, 1024 * 256);
  k_pack_wqkv<<<dim3(1536), dim3(256), 0, stream>>>(Wq, Wk, Wv, wqkv);
  k_pack_wke<<<dim3(1024), dim3(256), 0, stream>>>(Wk, wke);

  // --- qkv = node @ Wqkv (bf16 out, q pre-scaled) ---
  k_gemm<0, 1><<<dim3(32, 24, 1), dim3(256), 0, stream>>>(
      node_bf, wqkv, qkv, nullptr, 2048, 1536, 256, 256, 1536, 1536,
      0LL, 0LL, 0LL, 0LL, 0LL, 0LL);

  // --- qe = q @ blockdiag(WkE^T)  (fp32 out) ---
  k_gemm<0, 0><<<dim3(32, 8, 1), dim3(256), 0, stream>>>(
      qkv, wke, qe, nullptr, 2048, 512, 512, 1536, 512, 512,
      0LL, 0LL, 0LL, 0LL, 0LL, 0LL);

  // --- knT pack ---
  k_knT<<<dim3(4096), dim3(256), 0, stream>>>(qkv, knt);

  // --- logits = qe . edge  (write) ---
  k_edge<<<dim3(2048), dim3(256), 0, stream>>>(edge, qe, logits);

  // --- logits += q @ knT  (batched over (b,h), fp32 accumulate into C) ---
  k_gemm<1, 0><<<dim3(16, 16, 16), dim3(256), 0, stream>>>(
      qkv, knt, logits, nullptr, 1024, 1024, 64, 1536, 1024, 1024,
      1572864LL, 64LL, 524288LL, 65536LL, 8388608LL, 1048576LL);

  // --- softmax -> bf16 attn ---
  k_softmax<<<dim3(16384), dim3(256), 0, stream>>>(logits, attn);

  // --- mo = attn @ v  (batched, bf16 out, written as [b][n][h*64+o]) ---
  k_gemm<0, 1><<<dim3(16, 1, 16), dim3(256), 0, stream>>>(
      attn, qkv + 1024, mo, nullptr, 1024, 64, 1024, 1024, 1536, 512,
      8388608LL, 1048576LL, 1572864LL, 64LL, 524288LL, 64LL);

  // --- mha = mo @ Wp + bp  (fp32) ---
  k_gemm<2, 0><<<dim3(32, 4, 1), dim3(256), 0, stream>>>(
      mo, wp, mha, bp, 2048, 256, 512, 512, 256, 256,
      0LL, 0LL, 0LL, 0LL, 0LL, 0LL);

  // --- x = LN1(node + mha) -> xf (fp32), xb (bf16) ---
  k_ln<<<dim3(2048), dim3(256), 0, stream>>>(node, mha, g1, be1, xf, xb);

  // --- ffn hidden = relu(x @ W1 + b1)  (bf16) ---
  k_gemm<3, 1><<<dim3(32, 16, 1), dim3(256), 0, stream>>>(
      xb, w1, hb, b1, 2048, 1024, 256, 256, 1024, 1024,
      0LL, 0LL, 0LL, 0LL, 0LL, 0LL);

  // --- ff = hidden @ W2 + b2  (fp32) ---
  k_gemm<2, 0><<<dim3(32, 4, 1), dim3(256), 0, stream>>>(
      hb, w2, ff, b2, 2048, 256, 1024, 1024, 256, 256,
      0LL, 0LL, 0LL, 0LL, 0LL, 0LL);

  // --- out = LN2(x + ff)  (fp32 to d_out) ---
  k_ln<<<dim3(2048), dim3(256), 0, stream>>>(xf, ff, g2, be2, out, nullptr);
}

// Round 2
// 402.465 us; speedup vs baseline: 1.8074x; 1.8074x over previous
//
#include <hip/hip_runtime.h>
#include <hip/hip_bf16.h>

// Problem constants
#define B_  2
#define N_  1024
#define D_  256
#define E_  64
#define H_  8
#define HS_ 64
#define FF_ 1024
#define R_  (B_*N_)   // 2048 rows (b,n)

typedef short bf8 __attribute__((ext_vector_type(8)));   // 8 bf16 (bit pattern) = 4 VGPRs
typedef float f4  __attribute__((ext_vector_type(4)));

static __device__ __forceinline__ ushort f2b(float f) {
  __hip_bfloat16 h = __float2bfloat16(f);
  return *reinterpret_cast<ushort*>(&h);
}

// ---------------- pack / convert kernels ----------------

__global__ void k_cvt(const float* __restrict__ src, ushort* __restrict__ dst, int n) {
  int i = blockIdx.x * 256 + threadIdx.x;
  if (i < n) dst[i] = f2b(src[i]);
}

// Wqkv_packed [256 x 1536]: cols 0..511 = q (h,o) scaled 1/8, 512..1023 = k-node, 1024..1535 = v
__global__ void k_pack_wqkv(const float* __restrict__ Wq, const float* __restrict__ Wk,
                            const float* __restrict__ Wv, ushort* __restrict__ out) {
  int idx = blockIdx.x * 256 + threadIdx.x;   // 256*1536
  if (idx >= 256 * 1536) return;
  int i = idx / 1536, c = idx % 1536;
  int mat = c >> 9, h = (c >> 6) & 7, o = c & 63;
  float v;
  if (mat == 0)      v = Wq[(h * 256 + i) * 64 + o] * 0.125f;   // q scaled by 1/sqrt(HS)
  else if (mat == 1) v = Wk[(h * 320 + i) * 64 + o];            // Wk is [H][320][64]
  else               v = Wv[(h * 256 + i) * 64 + o];
  out[idx] = f2b(v);
}

// Block-diagonal WkE [512 x 512]: row=(h*64+o), col=(h2*64+e); nonzero iff h2==h -> WkE[h][e][o]
__global__ void k_pack_wke(const float* __restrict__ Wk, ushort* __restrict__ out) {
  int idx = blockIdx.x * 256 + threadIdx.x;   // 512*512
  if (idx >= 512 * 512) return;
  int row = idx >> 9, c = idx & 511;
  int h = row >> 6, o = row & 63;
  int h2 = c >> 6, e = c & 63;
  float v = (h2 == h) ? Wk[(h * 320 + 256 + e) * 64 + o] : 0.0f;
  out[idx] = f2b(v);
}

// knT[b][h][o][m] <- qkv[(b*1024+m)*1536 + 512 + h*64 + o]
__global__ void k_knT(const ushort* __restrict__ qkv, ushort* __restrict__ knt) {
  int idx = blockIdx.x * 256 + threadIdx.x;   // 16*64*1024 = 1048576
  if (idx >= 16 * 64 * 1024) return;
  int m = idx & 1023;
  int rest = idx >> 10;
  int o = rest & 63;
  int bh = rest >> 6;
  int b = bh >> 3, h = bh & 7;
  knt[idx] = qkv[(size_t)(b * 1024 + m) * 1536 + 512 + h * 64 + o];
}

// ---------------- generic bf16 MFMA GEMM ----------------
// C[M x N] = A[M x K] @ B[K x N]  (A,B bf16 row-major with strides; C fp32 or bf16)
// EPI: 0=none, 1=C+=, 2=+bias, 3=+bias,relu   OBF: 1 -> write bf16
// Batched via blockIdx.z: offset = (z>>3)*s1 + (z&7)*s2  (element offsets)
template<int EPI, int OBF>
__global__ void k_gemm(const ushort* __restrict__ A, const ushort* __restrict__ Bm,
                       void* __restrict__ Cv, const float* __restrict__ bias,
                       int M, int N, int K, int lda, int ldb, int ldc,
                       long long as1, long long as2, long long bs1, long long bs2,
                       long long cs1, long long cs2) {
  int z = blockIdx.z;
  const ushort* Ab = A + (size_t)((z >> 3) * as1 + (z & 7) * as2);
  const ushort* Bb = Bm + (size_t)((z >> 3) * bs1 + (z & 7) * bs2);
  size_t coff = (size_t)((z >> 3) * cs1 + (z & 7) * cs2);
  int r0 = blockIdx.x * 64, c0 = blockIdx.y * 64;

  __shared__ ushort As[64][40];   // +8 pad
  __shared__ ushort Bs[32][72];   // +8 pad

  int tid = threadIdx.x;
  int lane = tid & 63, w = tid >> 6;
  int wm = w >> 1, wn = w & 1;            // wave -> 32x32 quadrant
  int kg = lane >> 4, lr = lane & 15;

  f4 acc[2][2] = {};

  for (int k0 = 0; k0 < K; k0 += 32) {
    __syncthreads();
    { // stage A tile 64x32
      int row = tid >> 2, ch = tid & 3;
      *(int4*)&As[row][ch * 8] = *(const int4*)(Ab + (size_t)(r0 + row) * lda + k0 + ch * 8);
    }
    { // stage B tile 32x64
      int kk = tid >> 3, ch = tid & 7;
      *(int4*)&Bs[kk][ch * 8] = *(const int4*)(Bb + (size_t)(k0 + kk) * ldb + c0 + ch * 8);
    }
    __syncthreads();

    bf8 bfr[2];
    #pragma unroll
    for (int cb = 0; cb < 2; ++cb) {
      #pragma unroll
      for (int j = 0; j < 8; ++j)
        bfr[cb][j] = (short)Bs[kg * 8 + j][wn * 32 + cb * 16 + lr];  // B: col=l&15, k=8*kg+j
    }
    #pragma unroll
    for (int rb = 0; rb < 2; ++rb) {
      bf8 af = *(const bf8*)&As[wm * 32 + rb * 16 + lr][kg * 8];     // A: row=l&15, k=8*kg+j
      #pragma unroll
      for (int cb = 0; cb < 2; ++cb)
        acc[rb][cb] = __builtin_amdgcn_mfma_f32_16x16x32_bf16(af, bfr[cb], acc[rb][cb], 0, 0, 0);
    }
  }

  float* Cf = (float*)Cv;
  ushort* Cb = (ushort*)Cv;
  #pragma unroll
  for (int rb = 0; rb < 2; ++rb) {
    #pragma unroll
    for (int cb = 0; cb < 2; ++cb) {
      #pragma unroll
      for (int rr = 0; rr < 4; ++rr) {
        int row = r0 + wm * 32 + rb * 16 + kg * 4 + rr;   // D: col=l&15, row=4*kg+reg
        int col = c0 + wn * 32 + cb * 16 + lr;
        size_t ci = coff + (size_t)row * ldc + col;
        float v = acc[rb][cb][rr];
        if (EPI == 1) v += Cf[ci];
        if (EPI >= 2) v += bias[col];
        if (EPI == 3) v = fmaxf(v, 0.0f);
        if (OBF) Cb[ci] = f2b(v); else Cf[ci] = v;
      }
    }
  }
}

// ---------------- fused edge-logits + node-logits + softmax -> bf16 attn ----------------
// Per block (b,n): stream edge[b,n,:,:] (256 KB) once through double-buffered LDS,
// dot with qe (fp32), add precomputed node logits, block softmax per h, write attn bf16.
__global__ __launch_bounds__(256, 2) void k_fused(
    const float* __restrict__ edge, const float* __restrict__ qe,
    const float* __restrict__ logN, ushort* __restrict__ attn) {
  int bid = blockIdx.x;            // b*1024 + n
  int b = bid >> 10, n = bid & 1023;
  int t = threadIdx.x;
  int lane = t & 63, w = t >> 6;
  int r = t & 127, hf = t >> 7;    // 2 threads per row, e-halves of 32

  __shared__ float qes[512];
  __shared__ float buf[2][8192];   // 2 x 32 KB tiles (128 rows x 64 e), XOR-swizzled
  __shared__ float red[2][4][8];

  { float2 v = reinterpret_cast<const float2*>(qe + (size_t)bid * 512)[t];
    qes[t * 2] = v.x; qes[t * 2 + 1] = v.y; }

  const float* eb = edge + (size_t)bid * 65536;   // 1024 rows x 64 floats

  float acc[8][8];
  #pragma unroll
  for (int i = 0; i < 8; ++i)
    #pragma unroll
    for (int h = 0; h < 8; ++h) acc[i][h] = 0.f;

  // prefetch tile 0 into regs (8 float4 / thread, fully coalesced)
  float4 pf[8];
  #pragma unroll
  for (int u = 0; u < 8; ++u)
    pf[u] = reinterpret_cast<const float4*>(eb)[t + 256 * u];

  #pragma unroll
  for (int tl = 0; tl < 8; ++tl) {
    float* bc = buf[tl & 1];
    __syncthreads();               // prev compute on this buffer done; tile tl's loads complete
    #pragma unroll
    for (int u = 0; u < 8; ++u) {  // swizzled LDS write: [row][col ^ (row&15)]
      int g = t + 256 * u;
      int rl = g >> 4, c = t & 15;
      *reinterpret_cast<float4*>(&bc[rl * 64 + ((c ^ (rl & 15)) << 2)]) = pf[u];
    }
    if (tl < 7) {                  // issue next tile's loads; latency hides under compute
      const float4* src = reinterpret_cast<const float4*>(eb + (tl + 1) * 8192);
      #pragma unroll
      for (int u = 0; u < 8; ++u) pf[u] = src[t + 256 * u];
    }
    __syncthreads();               // LDS writes visible
    #pragma unroll
    for (int ec = 0; ec < 4; ++ec) {   // 8 e's per chunk within this thread's half
      float qv[8][8];
      #pragma unroll
      for (int h = 0; h < 8; ++h) {    // wave-uniform broadcasts
        float4 a  = *reinterpret_cast<const float4*>(&qes[h * 64 + hf * 32 + ec * 8]);
        float4 bq = *reinterpret_cast<const float4*>(&qes[h * 64 + hf * 32 + ec * 8 + 4]);
        qv[h][0]=a.x;  qv[h][1]=a.y;  qv[h][2]=a.z;  qv[h][3]=a.w;
        qv[h][4]=bq.x; qv[h][5]=bq.y; qv[h][6]=bq.z; qv[h][7]=bq.w;
      }
      int k0 = hf * 8 + ec * 2;
      float4 e0 = *reinterpret_cast<const float4*>(&bc[r * 64 + (((k0    ) ^ (r & 15)) << 2)]);
      float4 e1 = *reinterpret_cast<const float4*>(&bc[r * 64 + (((k0 + 1) ^ (r & 15)) << 2)]);
      #pragma unroll
      for (int h = 0; h < 8; ++h)
        acc[tl][h] += e0.x*qv[h][0] + e0.y*qv[h][1] + e0.z*qv[h][2] + e0.w*qv[h][3]
                    + e1.x*qv[h][4] + e1.y*qv[h][5] + e1.z*qv[h][6] + e1.w*qv[h][7];
    }
  }

  // ---- combine e-halves via LDS (pad 9: conflict-free) ----
  __syncthreads();
  float* comb = &buf[0][0];        // reuse tile buffers: 1024 rows x 9 floats = 36 KB
  if (hf) {
    #pragma unroll
    for (int tl = 0; tl < 8; ++tl)
      #pragma unroll
      for (int h = 0; h < 8; ++h)
        comb[(tl * 128 + r) * 9 + h] = acc[tl][h];
  }
  __syncthreads();
  if (!hf) {
    #pragma unroll
    for (int tl = 0; tl < 8; ++tl)
      #pragma unroll
      for (int h = 0; h < 8; ++h)
        acc[tl][h] += comb[(tl * 128 + r) * 9 + h];
  }
  __syncthreads();
  if (!hf) {
    #pragma unroll
    for (int tl = 0; tl < 8; ++tl)
      #pragma unroll
      for (int h = 0; h < 8; ++h)
        comb[(tl * 128 + r) * 9 + h] = acc[tl][h];
  }
  __syncthreads();

  // ---- all 256 threads: own m = t + 256j; add node logits; softmax per h ----
  float l[4][8];
  #pragma unroll
  for (int j = 0; j < 4; ++j) {
    int m = t + 256 * j;
    #pragma unroll
    for (int h = 0; h < 8; ++h)
      l[j][h] = comb[m * 9 + h] + logN[((size_t)(b * 8 + h) * 1024 + n) * 1024 + m];
  }
  float mx[8], sm[8];
  #pragma unroll
  for (int h = 0; h < 8; ++h) {
    float v = fmaxf(fmaxf(l[0][h], l[1][h]), fmaxf(l[2][h], l[3][h]));
    #pragma unroll
    for (int off = 32; off; off >>= 1) v = fmaxf(v, __shfl_xor(v, off));
    if (lane == 0) red[0][w][h] = v;
  }
  __syncthreads();
  #pragma unroll
  for (int h = 0; h < 8; ++h)
    mx[h] = fmaxf(fmaxf(red[0][0][h], red[0][1][h]), fmaxf(red[0][2][h], red[0][3][h]));
  #pragma unroll
  for (int j = 0; j < 4; ++j)
    #pragma unroll
    for (int h = 0; h < 8; ++h)
      l[j][h] = __expf(l[j][h] - mx[h]);
  #pragma unroll
  for (int h = 0; h < 8; ++h) {
    float v = l[0][h] + l[1][h] + l[2][h] + l[3][h];
    #pragma unroll
    for (int off = 32; off; off >>= 1) v += __shfl_xor(v, off);
    if (lane == 0) red[1][w][h] = v;
  }
  __syncthreads();
  #pragma unroll
  for (int h = 0; h < 8; ++h)
    sm[h] = 1.0f / (red[1][0][h] + red[1][1][h] + red[1][2][h] + red[1][3][h]);
  #pragma unroll
  for (int h = 0; h < 8; ++h) {
    size_t base = ((size_t)(b * 8 + h) * 1024 + n) * 1024;
    #pragma unroll
    for (int j = 0; j < 4; ++j)
      attn[base + t + 256 * j] = f2b(l[j][h] * sm[h]);
  }
}

// ---------------- residual + layernorm (D=256, one block per row) ----------------
__global__ void k_ln(const float* __restrict__ a, const float* __restrict__ bb,
                     const float* __restrict__ g, const float* __restrict__ be,
                     float* __restrict__ of, ushort* __restrict__ ob) {
  int r = blockIdx.x, i = threadIdx.x;
  float t = a[(size_t)r * 256 + i] + bb[(size_t)r * 256 + i];
  __shared__ float red[4];

  float s = t;
  for (int off = 32; off; off >>= 1) s += __shfl_xor(s, off);
  if ((i & 63) == 0) red[i >> 6] = s;
  __syncthreads();
  float mean = (red[0] + red[1] + red[2] + red[3]) * (1.0f / 256.0f);
  __syncthreads();

  float d = t - mean;
  float q = d * d;
  for (int off = 32; off; off >>= 1) q += __shfl_xor(q, off);
  if ((i & 63) == 0) red[i >> 6] = q;
  __syncthreads();
  float var = (red[0] + red[1] + red[2] + red[3]) * (1.0f / 256.0f);

  float y = d * rsqrtf(var + 1e-6f) * g[i] + be[i];
  of[(size_t)r * 256 + i] = y;
  if (ob) ob[(size_t)r * 256 + i] = f2b(y);
}

// ---------------- launch ----------------

extern "C" void kernel_launch(void* const* d_in, const int* in_sizes, int n_in,
                              void* d_out, int out_size, void* d_ws, size_t ws_size,
                              hipStream_t stream) {
  (void)in_sizes; (void)n_in; (void)out_size; (void)ws_size;
  const float* node = (const float*)d_in[0];
  const float* edge = (const float*)d_in[1];
  const float* Wq   = (const float*)d_in[2];
  const float* Wk   = (const float*)d_in[3];
  const float* Wv   = (const float*)d_in[4];
  const float* Wp   = (const float*)d_in[5];
  const float* bp   = (const float*)d_in[6];
  const float* g1   = (const float*)d_in[7];
  const float* be1  = (const float*)d_in[8];
  const float* W1   = (const float*)d_in[9];
  const float* b1   = (const float*)d_in[10];
  const float* W2   = (const float*)d_in[11];
  const float* b2   = (const float*)d_in[12];
  const float* g2   = (const float*)d_in[13];
  const float* be2  = (const float*)d_in[14];
  float* out = (float*)d_out;

  char* ws = (char*)d_ws;
  size_t off = 0;
  auto alloc = [&](size_t bytes) -> char* {
    char* p = ws + off;
    off = (off + bytes + 255) & ~(size_t)255;
    return p;
  };
  ushort* node_bf = (ushort*)alloc((size_t)R_ * D_ * 2);
  ushort* wqkv    = (ushort*)alloc((size_t)256 * 1536 * 2);
  ushort* wke     = (ushort*)alloc((size_t)512 * 512 * 2);
  ushort* wp      = (ushort*)alloc((size_t)512 * 256 * 2);
  ushort* w1      = (ushort*)alloc((size_t)256 * 1024 * 2);
  ushort* w2      = (ushort*)alloc((size_t)1024 * 256 * 2);
  ushort* qkv     = (ushort*)alloc((size_t)R_ * 1536 * 2);
  float*  qe      = (float*) alloc((size_t)R_ * 512 * 4);
  ushort* knt     = (ushort*)alloc((size_t)16 * 64 * 1024 * 2);
  float*  logits  = (float*) alloc((size_t)16 * 1024 * 1024 * 4); // node logits, fp32
  ushort* attn    = (ushort*)alloc((size_t)16 * 1024 * 1024 * 2);
  ushort* mo      = (ushort*)alloc((size_t)R_ * 512 * 2);
  float*  mha     = (float*) alloc((size_t)R_ * 256 * 4);
  float*  xf      = (float*) alloc((size_t)R_ * 256 * 4);
  ushort* xb      = (ushort*)alloc((size_t)R_ * 256 * 2);
  ushort* hb      = (ushort*)alloc((size_t)R_ * 1024 * 2);
  float*  ff      = (float*) alloc((size_t)R_ * 256 * 4);

  // --- pack / convert ---
  k_cvt<<<dim3((R_ * D_ + 255) / 256), dim3(256), 0, stream>>>(node, node_bf, R_ * D_);
  k_cvt<<<dim3((512 * 256 + 255) / 256), dim3(256), 0, stream>>>(Wp, wp, 512 * 256);
  k_cvt<<<dim3((256 * 1024 + 255) / 256), dim3(256), 0, stream>>>(W1, w1, 256 * 1024);
  k_cvt<<<dim3((1024 * 256 + 255) / 256), dim3(256), 0, stream>>>(W2, w2, 1024 * 256);
  k_pack_wqkv<<<dim3(1536), dim3(256), 0, stream>>>(Wq, Wk, Wv, wqkv);
  k_pack_wke<<<dim3(1024), dim3(256), 0, stream>>>(Wk, wke);

  // --- qkv = node @ Wqkv (bf16 out, q pre-scaled) ---
  k_gemm<0, 1><<<dim3(32, 24, 1), dim3(256), 0, stream>>>(
      node_bf, wqkv, qkv, nullptr, 2048, 1536, 256, 256, 1536, 1536,
      0LL, 0LL, 0LL, 0LL, 0LL, 0LL);

  // --- qe = q @ blockdiag(WkE^T)  (fp32 out) ---
  k_gemm<0, 0><<<dim3(32, 8, 1), dim3(256), 0, stream>>>(
      qkv, wke, qe, nullptr, 2048, 512, 512, 1536, 512, 512,
      0LL, 0LL, 0LL, 0LL, 0LL, 0LL);

  // --- knT pack ---
  k_knT<<<dim3(4096), dim3(256), 0, stream>>>(qkv, knt);

  // --- node logits = q @ knT  (batched over (b,h), WRITE fp32) ---
  k_gemm<0, 0><<<dim3(16, 16, 16), dim3(256), 0, stream>>>(
      qkv, knt, logits, nullptr, 1024, 1024, 64, 1536, 1024, 1024,
      1572864LL, 64LL, 524288LL, 65536LL, 8388608LL, 1048576LL);

  // --- fused: edge dot + node logits + softmax -> bf16 attn ---
  k_fused<<<dim3(2048), dim3(256), 0, stream>>>(edge, qe, logits, attn);

  // --- mo = attn @ v  (batched, bf16 out, written as [b][n][h*64+o]) ---
  k_gemm<0, 1><<<dim3(16, 1, 16), dim3(256), 0, stream>>>(
      attn, qkv + 1024, mo, nullptr, 1024, 64, 1024, 1024, 1536, 512,
      8388608LL, 1048576LL, 1572864LL, 64LL, 524288LL, 64LL);

  // --- mha = mo @ Wp + bp  (fp32) ---
  k_gemm<2, 0><<<dim3(32, 4, 1), dim3(256), 0, stream>>>(
      mo, wp, mha, bp, 2048, 256, 512, 512, 256, 256,
      0LL, 0LL, 0LL, 0LL, 0LL, 0LL);

  // --- x = LN1(node + mha) -> xf (fp32), xb (bf16) ---
  k_ln<<<dim3(2048), dim3(256), 0, stream>>>(node, mha, g1, be1, xf, xb);

  // --- ffn hidden = relu(x @ W1 + b1)  (bf16) ---
  k_gemm<3, 1><<<dim3(32, 16, 1), dim3(256), 0, stream>>>(
      xb, w1, hb, b1, 2048, 1024, 256, 256, 1024, 1024,
      0LL, 0LL, 0LL, 0LL, 0LL, 0LL);

  // --- ff = hidden @ W2 + b2  (fp32) ---
  k_gemm<2, 0><<<dim3(32, 4, 1), dim3(256), 0, stream>>>(
      hb, w2, ff, b2, 2048, 256, 1024, 1024, 256, 256,
      0LL, 0LL, 0LL, 0LL, 0LL, 0LL);

  // --- out = LN2(x + ff)  (fp32 to d_out) ---
  k_ln<<<dim3(2048), dim3(256), 0, stream>>>(xf, ff, g2, be2, out, nullptr);
}

// Round 3
// 396.086 us; speedup vs baseline: 1.8365x; 1.0161x over previous
//
#include <hip/hip_runtime.h>
#include <hip/hip_bf16.h>

// Problem constants
#define B_  2
#define N_  1024
#define D_  256
#define E_  64
#define H_  8
#define HS_ 64
#define FF_ 1024
#define R_  (B_*N_)   // 2048 rows (b,n)

typedef short bf8 __attribute__((ext_vector_type(8)));   // 8 bf16 (bit pattern) = 4 VGPRs
typedef float f4  __attribute__((ext_vector_type(4)));

static __device__ __forceinline__ ushort f2b(float f) {
  __hip_bfloat16 h = __float2bfloat16(f);
  return *reinterpret_cast<ushort*>(&h);
}

// ---------------- pack / convert kernels ----------------

__global__ void k_cvt(const float* __restrict__ src, ushort* __restrict__ dst, int n) {
  int i = blockIdx.x * 256 + threadIdx.x;
  if (i < n) dst[i] = f2b(src[i]);
}

// Wqkv_packed [256 x 1536]: cols 0..511 = q (h,o) scaled 1/8, 512..1023 = k-node, 1024..1535 = v
__global__ void k_pack_wqkv(const float* __restrict__ Wq, const float* __restrict__ Wk,
                            const float* __restrict__ Wv, ushort* __restrict__ out) {
  int idx = blockIdx.x * 256 + threadIdx.x;   // 256*1536
  if (idx >= 256 * 1536) return;
  int i = idx / 1536, c = idx % 1536;
  int mat = c >> 9, h = (c >> 6) & 7, o = c & 63;
  float v;
  if (mat == 0)      v = Wq[(h * 256 + i) * 64 + o] * 0.125f;   // q scaled by 1/sqrt(HS)
  else if (mat == 1) v = Wk[(h * 320 + i) * 64 + o];            // Wk is [H][320][64]
  else               v = Wv[(h * 256 + i) * 64 + o];
  out[idx] = f2b(v);
}

// Block-diagonal WkE [512 x 512]: row=(h*64+o), col=(h2*64+e); nonzero iff h2==h -> WkE[h][e][o]
__global__ void k_pack_wke(const float* __restrict__ Wk, ushort* __restrict__ out) {
  int idx = blockIdx.x * 256 + threadIdx.x;   // 512*512
  if (idx >= 512 * 512) return;
  int row = idx >> 9, c = idx & 511;
  int h = row >> 6, o = row & 63;
  int h2 = c >> 6, e = c & 63;
  float v = (h2 == h) ? Wk[(h * 320 + 256 + e) * 64 + o] : 0.0f;
  out[idx] = f2b(v);
}

// knT[b][h][o][m] <- qkv[(b*1024+m)*1536 + 512 + h*64 + o]
__global__ void k_knT(const ushort* __restrict__ qkv, ushort* __restrict__ knt) {
  int idx = blockIdx.x * 256 + threadIdx.x;   // 16*64*1024 = 1048576
  if (idx >= 16 * 64 * 1024) return;
  int m = idx & 1023;
  int rest = idx >> 10;
  int o = rest & 63;
  int bh = rest >> 6;
  int b = bh >> 3, h = bh & 7;
  knt[idx] = qkv[(size_t)(b * 1024 + m) * 1536 + 512 + h * 64 + o];
}

// ---------------- generic bf16 MFMA GEMM ----------------
// C[M x N] = A[M x K] @ B[K x N]  (A,B bf16 row-major with strides; C fp32 or bf16)
// EPI: 0=none, 1=C+=, 2=+bias, 3=+bias,relu   OBF: 1 -> write bf16
// Batched via blockIdx.z: offset = (z>>3)*s1 + (z&7)*s2  (element offsets)
template<int EPI, int OBF>
__global__ void k_gemm(const ushort* __restrict__ A, const ushort* __restrict__ Bm,
                       void* __restrict__ Cv, const float* __restrict__ bias,
                       int M, int N, int K, int lda, int ldb, int ldc,
                       long long as1, long long as2, long long bs1, long long bs2,
                       long long cs1, long long cs2) {
  int z = blockIdx.z;
  const ushort* Ab = A + (size_t)((z >> 3) * as1 + (z & 7) * as2);
  const ushort* Bb = Bm + (size_t)((z >> 3) * bs1 + (z & 7) * bs2);
  size_t coff = (size_t)((z >> 3) * cs1 + (z & 7) * cs2);
  int r0 = blockIdx.x * 64, c0 = blockIdx.y * 64;

  __shared__ ushort As[64][40];   // +8 pad
  __shared__ ushort Bs[32][72];   // +8 pad

  int tid = threadIdx.x;
  int lane = tid & 63, w = tid >> 6;
  int wm = w >> 1, wn = w & 1;            // wave -> 32x32 quadrant
  int kg = lane >> 4, lr = lane & 15;

  f4 acc[2][2] = {};

  for (int k0 = 0; k0 < K; k0 += 32) {
    __syncthreads();
    { // stage A tile 64x32
      int row = tid >> 2, ch = tid & 3;
      *(int4*)&As[row][ch * 8] = *(const int4*)(Ab + (size_t)(r0 + row) * lda + k0 + ch * 8);
    }
    { // stage B tile 32x64
      int kk = tid >> 3, ch = tid & 7;
      *(int4*)&Bs[kk][ch * 8] = *(const int4*)(Bb + (size_t)(k0 + kk) * ldb + c0 + ch * 8);
    }
    __syncthreads();

    bf8 bfr[2];
    #pragma unroll
    for (int cb = 0; cb < 2; ++cb) {
      #pragma unroll
      for (int j = 0; j < 8; ++j)
        bfr[cb][j] = (short)Bs[kg * 8 + j][wn * 32 + cb * 16 + lr];  // B: col=l&15, k=8*kg+j
    }
    #pragma unroll
    for (int rb = 0; rb < 2; ++rb) {
      bf8 af = *(const bf8*)&As[wm * 32 + rb * 16 + lr][kg * 8];     // A: row=l&15, k=8*kg+j
      #pragma unroll
      for (int cb = 0; cb < 2; ++cb)
        acc[rb][cb] = __builtin_amdgcn_mfma_f32_16x16x32_bf16(af, bfr[cb], acc[rb][cb], 0, 0, 0);
    }
  }

  float* Cf = (float*)Cv;
  ushort* Cb = (ushort*)Cv;
  #pragma unroll
  for (int rb = 0; rb < 2; ++rb) {
    #pragma unroll
    for (int cb = 0; cb < 2; ++cb) {
      #pragma unroll
      for (int rr = 0; rr < 4; ++rr) {
        int row = r0 + wm * 32 + rb * 16 + kg * 4 + rr;   // D: col=l&15, row=4*kg+reg
        int col = c0 + wn * 32 + cb * 16 + lr;
        size_t ci = coff + (size_t)row * ldc + col;
        float v = acc[rb][cb][rr];
        if (EPI == 1) v += Cf[ci];
        if (EPI >= 2) v += bias[col];
        if (EPI == 3) v = fmaxf(v, 0.0f);
        if (OBF) Cb[ci] = f2b(v); else Cf[ci] = v;
      }
    }
  }
}

// ---------------- fused edge-logits + node-logits + softmax -> bf16 attn ----------------
// Per block (b,n): stream edge[b,n,:,:] (256 KB) once through LDS (reg-prefetch
// double-buffer), dot with qe, accumulate per-tile partials into an LDS logits
// buffer (lg[1024][9], 8 regs live per thread), add node logits, softmax, write bf16.
__global__ __launch_bounds__(256, 2) void k_fused(
    const float* __restrict__ edge, const float* __restrict__ qe,
    const float* __restrict__ logN, ushort* __restrict__ attn) {
  int bid = blockIdx.x;            // b*1024 + n
  int b = bid >> 10, n = bid & 1023;
  int t = threadIdx.x;
  int lane = t & 63, w = t >> 6;
  int r = t & 127, hf = t >> 7;    // 2 threads per m-row; e-halves of 32

  __shared__ float qes[512];       // qe row [h*64+e]
  __shared__ float stage[8192];    // 128 rows x 64 e fp32, XOR-swizzled
  __shared__ float lg[1024 * 9];   // block logits [m][h], pad-9 (gcd(9,32)=1)
  __shared__ float red[2][4][8];

  { float2 v = reinterpret_cast<const float2*>(qe + (size_t)bid * 512)[t];
    qes[t * 2] = v.x; qes[t * 2 + 1] = v.y; }

  const float* eb = edge + (size_t)bid * 65536;   // 1024 rows x 64 floats

  // prefetch tile 0 (8 float4/thread, fully coalesced)
  float4 pf[8];
  #pragma unroll
  for (int u = 0; u < 8; ++u)
    pf[u] = reinterpret_cast<const float4*>(eb)[t + 256 * u];

  #pragma unroll 1
  for (int tl = 0; tl < 8; ++tl) {
    __syncthreads();               // prev tile's compute done; qes visible at tl=0
    #pragma unroll
    for (int u = 0; u < 8; ++u) {  // swizzled LDS write: [row][slot ^ (row&15)]
      int g = t + 256 * u;
      int rl = g >> 4, c = t & 15;
      *reinterpret_cast<float4*>(&stage[rl * 64 + ((c ^ (rl & 15)) << 2)]) = pf[u];
    }
    if (tl < 7) {                  // issue next tile's loads; hide under compute
      const float4* src = reinterpret_cast<const float4*>(eb + (tl + 1) * 8192);
      #pragma unroll
      for (int u = 0; u < 8; ++u) pf[u] = src[t + 256 * u];
    }
    __syncthreads();               // stage visible

    float acc[8] = {};
    #pragma unroll
    for (int ec = 0; ec < 4; ++ec) {
      int k0 = hf * 8 + ec * 2;    // float4-slot index
      float4 e0 = *reinterpret_cast<const float4*>(&stage[r * 64 + (((k0    ) ^ (r & 15)) << 2)]);
      float4 e1 = *reinterpret_cast<const float4*>(&stage[r * 64 + (((k0 + 1) ^ (r & 15)) << 2)]);
      #pragma unroll
      for (int h = 0; h < 8; ++h) {  // wave-uniform LDS broadcasts
        float4 a  = *reinterpret_cast<const float4*>(&qes[h * 64 + hf * 32 + ec * 8]);
        float4 bq = *reinterpret_cast<const float4*>(&qes[h * 64 + hf * 32 + ec * 8 + 4]);
        acc[h] += e0.x*a.x  + e0.y*a.y  + e0.z*a.z  + e0.w*a.w
                + e1.x*bq.x + e1.y*bq.y + e1.z*bq.z + e1.w*bq.w;
      }
    }

    // combine e-halves into lg (stride-9: 2-way bank alias, free)
    int m = tl * 128 + r;
    if (hf) {
      #pragma unroll
      for (int h = 0; h < 8; ++h) lg[m * 9 + h] = acc[h];
    }
    __syncthreads();
    if (!hf) {
      #pragma unroll
      for (int h = 0; h < 8; ++h) lg[m * 9 + h] += acc[h];
    }
  }
  __syncthreads();                 // lg complete

  // ---- softmax: thread owns m = t + 256j; add node logits ----
  float l[4][8];
  #pragma unroll
  for (int j = 0; j < 4; ++j) {
    int m = t + 256 * j;
    #pragma unroll
    for (int h = 0; h < 8; ++h)
      l[j][h] = lg[m * 9 + h] + logN[((size_t)(b * 8 + h) * 1024 + n) * 1024 + m];
  }
  float mx[8], sm[8];
  #pragma unroll
  for (int h = 0; h < 8; ++h) {
    float v = fmaxf(fmaxf(l[0][h], l[1][h]), fmaxf(l[2][h], l[3][h]));
    #pragma unroll
    for (int off = 32; off; off >>= 1) v = fmaxf(v, __shfl_xor(v, off));
    if (lane == 0) red[0][w][h] = v;
  }
  __syncthreads();
  #pragma unroll
  for (int h = 0; h < 8; ++h)
    mx[h] = fmaxf(fmaxf(red[0][0][h], red[0][1][h]), fmaxf(red[0][2][h], red[0][3][h]));
  #pragma unroll
  for (int j = 0; j < 4; ++j)
    #pragma unroll
    for (int h = 0; h < 8; ++h)
      l[j][h] = __expf(l[j][h] - mx[h]);
  #pragma unroll
  for (int h = 0; h < 8; ++h) {
    float v = l[0][h] + l[1][h] + l[2][h] + l[3][h];
    #pragma unroll
    for (int off = 32; off; off >>= 1) v += __shfl_xor(v, off);
    if (lane == 0) red[1][w][h] = v;
  }
  __syncthreads();
  #pragma unroll
  for (int h = 0; h < 8; ++h)
    sm[h] = 1.0f / (red[1][0][h] + red[1][1][h] + red[1][2][h] + red[1][3][h]);
  #pragma unroll
  for (int h = 0; h < 8; ++h) {
    size_t base = ((size_t)(b * 8 + h) * 1024 + n) * 1024;
    #pragma unroll
    for (int j = 0; j < 4; ++j)
      attn[base + t + 256 * j] = f2b(l[j][h] * sm[h]);
  }
}

// ---------------- residual + layernorm (D=256, one block per row) ----------------
__global__ void k_ln(const float* __restrict__ a, const float* __restrict__ bb,
                     const float* __restrict__ g, const float* __restrict__ be,
                     float* __restrict__ of, ushort* __restrict__ ob) {
  int r = blockIdx.x, i = threadIdx.x;
  float t = a[(size_t)r * 256 + i] + bb[(size_t)r * 256 + i];
  __shared__ float red[4];

  float s = t;
  for (int off = 32; off; off >>= 1) s += __shfl_xor(s, off);
  if ((i & 63) == 0) red[i >> 6] = s;
  __syncthreads();
  float mean = (red[0] + red[1] + red[2] + red[3]) * (1.0f / 256.0f);
  __syncthreads();

  float d = t - mean;
  float q = d * d;
  for (int off = 32; off; off >>= 1) q += __shfl_xor(q, off);
  if ((i & 63) == 0) red[i >> 6] = q;
  __syncthreads();
  float var = (red[0] + red[1] + red[2] + red[3]) * (1.0f / 256.0f);

  float y = d * rsqrtf(var + 1e-6f) * g[i] + be[i];
  of[(size_t)r * 256 + i] = y;
  if (ob) ob[(size_t)r * 256 + i] = f2b(y);
}

// ---------------- launch ----------------

extern "C" void kernel_launch(void* const* d_in, const int* in_sizes, int n_in,
                              void* d_out, int out_size, void* d_ws, size_t ws_size,
                              hipStream_t stream) {
  (void)in_sizes; (void)n_in; (void)out_size; (void)ws_size;
  const float* node = (const float*)d_in[0];
  const float* edge = (const float*)d_in[1];
  const float* Wq   = (const float*)d_in[2];
  const float* Wk   = (const float*)d_in[3];
  const float* Wv   = (const float*)d_in[4];
  const float* Wp   = (const float*)d_in[5];
  const float* bp   = (const float*)d_in[6];
  const float* g1   = (const float*)d_in[7];
  const float* be1  = (const float*)d_in[8];
  const float* W1   = (const float*)d_in[9];
  const float* b1   = (const float*)d_in[10];
  const float* W2   = (const float*)d_in[11];
  const float* b2   = (const float*)d_in[12];
  const float* g2   = (const float*)d_in[13];
  const float* be2  = (const float*)d_in[14];
  float* out = (float*)d_out;

  char* ws = (char*)d_ws;
  size_t off = 0;
  auto alloc = [&](size_t bytes) -> char* {
    char* p = ws + off;
    off = (off + bytes + 255) & ~(size_t)255;
    return p;
  };
  ushort* node_bf = (ushort*)alloc((size_t)R_ * D_ * 2);
  ushort* wqkv    = (ushort*)alloc((size_t)256 * 1536 * 2);
  ushort* wke     = (ushort*)alloc((size_t)512 * 512 * 2);
  ushort* wp      = (ushort*)alloc((size_t)512 * 256 * 2);
  ushort* w1      = (ushort*)alloc((size_t)256 * 1024 * 2);
  ushort* w2      = (ushort*)alloc((size_t)1024 * 256 * 2);
  ushort* qkv     = (ushort*)alloc((size_t)R_ * 1536 * 2);
  float*  qe      = (float*) alloc((size_t)R_ * 512 * 4);
  ushort* knt     = (ushort*)alloc((size_t)16 * 64 * 1024 * 2);
  float*  logits  = (float*) alloc((size_t)16 * 1024 * 1024 * 4); // node logits, fp32
  ushort* attn    = (ushort*)alloc((size_t)16 * 1024 * 1024 * 2);
  ushort* mo      = (ushort*)alloc((size_t)R_ * 512 * 2);
  float*  mha     = (float*) alloc((size_t)R_ * 256 * 4);
  float*  xf      = (float*) alloc((size_t)R_ * 256 * 4);
  ushort* xb      = (ushort*)alloc((size_t)R_ * 256 * 2);
  ushort* hb      = (ushort*)alloc((size_t)R_ * 1024 * 2);
  float*  ff      = (float*) alloc((size_t)R_ * 256 * 4);

  // --- pack / convert ---
  k_cvt<<<dim3((R_ * D_ + 255) / 256), dim3(256), 0, stream>>>(node, node_bf, R_ * D_);
  k_cvt<<<dim3((512 * 256 + 255) / 256), dim3(256), 0, stream>>>(Wp, wp, 512 * 256);
  k_cvt<<<dim3((256 * 1024 + 255) / 256), dim3(256), 0, stream>>>(W1, w1, 256 * 1024);
  k_cvt<<<dim3((1024 * 256 + 255) / 256), dim3(256), 0, stream>>>(W2, w2, 1024 * 256);
  k_pack_wqkv<<<dim3(1536), dim3(256), 0, stream>>>(Wq, Wk, Wv, wqkv);
  k_pack_wke<<<dim3(1024), dim3(256), 0, stream>>>(Wk, wke);

  // --- qkv = node @ Wqkv (bf16 out, q pre-scaled) ---
  k_gemm<0, 1><<<dim3(32, 24, 1), dim3(256), 0, stream>>>(
      node_bf, wqkv, qkv, nullptr, 2048, 1536, 256, 256, 1536, 1536,
      0LL, 0LL, 0LL, 0LL, 0LL, 0LL);

  // --- qe = q @ blockdiag(WkE^T)  (fp32 out) ---
  k_gemm<0, 0><<<dim3(32, 8, 1), dim3(256), 0, stream>>>(
      qkv, wke, qe, nullptr, 2048, 512, 512, 1536, 512, 512,
      0LL, 0LL, 0LL, 0LL, 0LL, 0LL);

  // --- knT pack ---
  k_knT<<<dim3(4096), dim3(256), 0, stream>>>(qkv, knt);

  // --- node logits = q @ knT  (batched over (b,h), WRITE fp32) ---
  k_gemm<0, 0><<<dim3(16, 16, 16), dim3(256), 0, stream>>>(
      qkv, knt, logits, nullptr, 1024, 1024, 64, 1536, 1024, 1024,
      1572864LL, 64LL, 524288LL, 65536LL, 8388608LL, 1048576LL);

  // --- fused: edge dot + node logits + softmax -> bf16 attn ---
  k_fused<<<dim3(2048), dim3(256), 0, stream>>>(edge, qe, logits, attn);

  // --- mo = attn @ v  (batched, bf16 out, written as [b][n][h*64+o]) ---
  k_gemm<0, 1><<<dim3(16, 1, 16), dim3(256), 0, stream>>>(
      attn, qkv + 1024, mo, nullptr, 1024, 64, 1024, 1024, 1536, 512,
      8388608LL, 1048576LL, 1572864LL, 64LL, 524288LL, 64LL);

  // --- mha = mo @ Wp + bp  (fp32) ---
  k_gemm<2, 0><<<dim3(32, 4, 1), dim3(256), 0, stream>>>(
      mo, wp, mha, bp, 2048, 256, 512, 512, 256, 256,
      0LL, 0LL, 0LL, 0LL, 0LL, 0LL);

  // --- x = LN1(node + mha) -> xf (fp32), xb (bf16) ---
  k_ln<<<dim3(2048), dim3(256), 0, stream>>>(node, mha, g1, be1, xf, xb);

  // --- ffn hidden = relu(x @ W1 + b1)  (bf16) ---
  k_gemm<3, 1><<<dim3(32, 16, 1), dim3(256), 0, stream>>>(
      xb, w1, hb, b1, 2048, 1024, 256, 256, 1024, 1024,
      0LL, 0LL, 0LL, 0LL, 0LL, 0LL);

  // --- ff = hidden @ W2 + b2  (fp32) ---
  k_gemm<2, 0><<<dim3(32, 4, 1), dim3(256), 0, stream>>>(
      hb, w2, ff, b2, 2048, 256, 1024, 1024, 256, 256,
      0LL, 0LL, 0LL, 0LL, 0LL, 0LL);

  // --- out = LN2(x + ff)  (fp32 to d_out) ---
  k_ln<<<dim3(2048), dim3(256), 0, stream>>>(xf, ff, g2, be2, out, nullptr);
}

// Round 4
// 283.930 us; speedup vs baseline: 2.5619x; 1.3950x over previous
//
#include <hip/hip_runtime.h>
#include <hip/hip_bf16.h>

// Problem constants
#define B_  2
#define N_  1024
#define D_  256
#define E_  64
#define H_  8
#define HS_ 64
#define FF_ 1024
#define R_  (B_*N_)   // 2048 rows (b,n)

typedef short bf8 __attribute__((ext_vector_type(8)));   // 8 bf16 (bit pattern) = 4 VGPRs
typedef float f4  __attribute__((ext_vector_type(4)));

static __device__ __forceinline__ ushort f2b(float f) {
  __hip_bfloat16 h = __float2bfloat16(f);
  return *reinterpret_cast<ushort*>(&h);
}

static __device__ __forceinline__ ushort4 f4_to_b4(float4 v) {
  ushort4 r;
  r.x = f2b(v.x); r.y = f2b(v.y); r.z = f2b(v.z); r.w = f2b(v.w);
  return r;
}

// ---------------- pack / convert kernels ----------------

__global__ void k_cvt(const float* __restrict__ src, ushort* __restrict__ dst, int n) {
  int i = blockIdx.x * 256 + threadIdx.x;
  if (i < n) dst[i] = f2b(src[i]);
}

// Wqkv_packed [256 x 1536]: cols 0..511 = q (h,o) scaled 1/8, 512..1023 = k-node, 1024..1535 = v
__global__ void k_pack_wqkv(const float* __restrict__ Wq, const float* __restrict__ Wk,
                            const float* __restrict__ Wv, ushort* __restrict__ out) {
  int idx = blockIdx.x * 256 + threadIdx.x;   // 256*1536
  if (idx >= 256 * 1536) return;
  int i = idx / 1536, c = idx % 1536;
  int mat = c >> 9, h = (c >> 6) & 7, o = c & 63;
  float v;
  if (mat == 0)      v = Wq[(h * 256 + i) * 64 + o] * 0.125f;   // q scaled by 1/sqrt(HS)
  else if (mat == 1) v = Wk[(h * 320 + i) * 64 + o];            // Wk is [H][320][64]
  else               v = Wv[(h * 256 + i) * 64 + o];
  out[idx] = f2b(v);
}

// Block-diagonal WkE [512 x 512]: row=(h*64+o), col=(h2*64+e); nonzero iff h2==h -> WkE[h][e][o]
__global__ void k_pack_wke(const float* __restrict__ Wk, ushort* __restrict__ out) {
  int idx = blockIdx.x * 256 + threadIdx.x;   // 512*512
  if (idx >= 512 * 512) return;
  int row = idx >> 9, c = idx & 511;
  int h = row >> 6, o = row & 63;
  int h2 = c >> 6, e = c & 63;
  float v = (h2 == h) ? Wk[(h * 320 + 256 + e) * 64 + o] : 0.0f;
  out[idx] = f2b(v);
}

// knT[b][h][o][m] <- qkv[(b*1024+m)*1536 + 512 + h*64 + o]
__global__ void k_knT(const ushort* __restrict__ qkv, ushort* __restrict__ knt) {
  int idx = blockIdx.x * 256 + threadIdx.x;   // 16*64*1024 = 1048576
  if (idx >= 16 * 64 * 1024) return;
  int m = idx & 1023;
  int rest = idx >> 10;
  int o = rest & 63;
  int bh = rest >> 6;
  int b = bh >> 3, h = bh & 7;
  knt[idx] = qkv[(size_t)(b * 1024 + m) * 1536 + 512 + h * 64 + o];
}

// ---------------- generic bf16 MFMA GEMM ----------------
// C[M x N] = A[M x K] @ B[K x N]  (A,B bf16 row-major with strides; C fp32 or bf16)
// EPI: 0=none, 1=C+=, 2=+bias, 3=+bias,relu   OBF: 1 -> write bf16
// Batched via blockIdx.z: offset = (z>>3)*s1 + (z&7)*s2  (element offsets)
template<int EPI, int OBF>
__global__ void k_gemm(const ushort* __restrict__ A, const ushort* __restrict__ Bm,
                       void* __restrict__ Cv, const float* __restrict__ bias,
                       int M, int N, int K, int lda, int ldb, int ldc,
                       long long as1, long long as2, long long bs1, long long bs2,
                       long long cs1, long long cs2) {
  int z = blockIdx.z;
  const ushort* Ab = A + (size_t)((z >> 3) * as1 + (z & 7) * as2);
  const ushort* Bb = Bm + (size_t)((z >> 3) * bs1 + (z & 7) * bs2);
  size_t coff = (size_t)((z >> 3) * cs1 + (z & 7) * cs2);
  int r0 = blockIdx.x * 64, c0 = blockIdx.y * 64;

  __shared__ ushort As[64][40];   // +8 pad
  __shared__ ushort Bs[32][72];   // +8 pad

  int tid = threadIdx.x;
  int lane = tid & 63, w = tid >> 6;
  int wm = w >> 1, wn = w & 1;            // wave -> 32x32 quadrant
  int kg = lane >> 4, lr = lane & 15;

  f4 acc[2][2] = {};

  for (int k0 = 0; k0 < K; k0 += 32) {
    __syncthreads();
    { // stage A tile 64x32
      int row = tid >> 2, ch = tid & 3;
      *(int4*)&As[row][ch * 8] = *(const int4*)(Ab + (size_t)(r0 + row) * lda + k0 + ch * 8);
    }
    { // stage B tile 32x64
      int kk = tid >> 3, ch = tid & 7;
      *(int4*)&Bs[kk][ch * 8] = *(const int4*)(Bb + (size_t)(k0 + kk) * ldb + c0 + ch * 8);
    }
    __syncthreads();

    bf8 bfr[2];
    #pragma unroll
    for (int cb = 0; cb < 2; ++cb) {
      #pragma unroll
      for (int j = 0; j < 8; ++j)
        bfr[cb][j] = (short)Bs[kg * 8 + j][wn * 32 + cb * 16 + lr];  // B: col=l&15, k=8*kg+j
    }
    #pragma unroll
    for (int rb = 0; rb < 2; ++rb) {
      bf8 af = *(const bf8*)&As[wm * 32 + rb * 16 + lr][kg * 8];     // A: row=l&15, k=8*kg+j
      #pragma unroll
      for (int cb = 0; cb < 2; ++cb)
        acc[rb][cb] = __builtin_amdgcn_mfma_f32_16x16x32_bf16(af, bfr[cb], acc[rb][cb], 0, 0, 0);
    }
  }

  float* Cf = (float*)Cv;
  ushort* Cb = (ushort*)Cv;
  #pragma unroll
  for (int rb = 0; rb < 2; ++rb) {
    #pragma unroll
    for (int cb = 0; cb < 2; ++cb) {
      #pragma unroll
      for (int rr = 0; rr < 4; ++rr) {
        int row = r0 + wm * 32 + rb * 16 + kg * 4 + rr;   // D: col=l&15, row=4*kg+reg
        int col = c0 + wn * 32 + cb * 16 + lr;
        size_t ci = coff + (size_t)row * ldc + col;
        float v = acc[rb][cb][rr];
        if (EPI == 1) v += Cf[ci];
        if (EPI >= 2) v += bias[col];
        if (EPI == 3) v = fmaxf(v, 0.0f);
        if (OBF) Cb[ci] = f2b(v); else Cf[ci] = v;
      }
    }
  }
}

// ---------------- fused edge-logits (MFMA) + node-logits + softmax -> bf16 attn ----------------
// Per block (b,n): stream edge[b,n,:,:] (256 KB fp32) once; cvt to bf16 into a
// swizzled LDS tile; lgE[m,h] = edge_tile @ qe^T via mfma_16x16x32 (B-frags held
// in regs, built once); logits to LDS lg[1024][9]; add node logits; softmax; bf16 attn.
__global__ __launch_bounds__(256, 3) void k_fused(
    const float* __restrict__ edge, const float* __restrict__ qe,
    const float* __restrict__ logN, ushort* __restrict__ attn) {
  int bid = blockIdx.x;            // b*1024 + n
  int b = bid >> 10, n = bid & 1023;
  int t = threadIdx.x;
  int lane = t & 63, w = t >> 6;
  int kg = lane >> 4, lr = lane & 15;

  __shared__ ushort As[128 * 64];  // 16 KB bf16 stage, slot^(row&7) swizzle
  __shared__ float lg[1024 * 9];   // block logits [m][h], pad-9 (gcd(9,32)=1)
  __shared__ float red[2][4][8];

  // ---- B fragments (qe row -> bf16), built once, kept in 8 VGPRs ----
  // B[k=e][col=h]: lane l holds B[kk*32 + 8*kg + j][lr]; lanes lr>=8 duplicate
  // lr&7 (their D-cols are discarded).
  bf8 bq[2];
  {
    const float* qrow = qe + (size_t)bid * 512 + (size_t)(lr & 7) * 64;
    #pragma unroll
    for (int kk = 0; kk < 2; ++kk) {
      float4 a  = *reinterpret_cast<const float4*>(&qrow[kk * 32 + kg * 8]);
      float4 c4 = *reinterpret_cast<const float4*>(&qrow[kk * 32 + kg * 8 + 4]);
      bq[kk][0] = (short)f2b(a.x);  bq[kk][1] = (short)f2b(a.y);
      bq[kk][2] = (short)f2b(a.z);  bq[kk][3] = (short)f2b(a.w);
      bq[kk][4] = (short)f2b(c4.x); bq[kk][5] = (short)f2b(c4.y);
      bq[kk][6] = (short)f2b(c4.z); bq[kk][7] = (short)f2b(c4.w);
    }
  }

  const float* eb = edge + (size_t)bid * 65536;   // 1024 rows x 64 floats

  // prefetch tile 0 (8 float4/thread, fully coalesced)
  float4 pf[8];
  #pragma unroll
  for (int u = 0; u < 8; ++u)
    pf[u] = reinterpret_cast<const float4*>(eb)[t + 256 * u];

  #pragma unroll 1
  for (int tl = 0; tl < 8; ++tl) {
    __syncthreads();               // prev tile's A-frag reads done
    #pragma unroll
    for (int u = 0; u < 8; ++u) {  // cvt fp32->bf16, swizzled write: slot ^= row&7
      int g = t + 256 * u;
      int rl = g >> 4, c = t & 15;          // row 0..127, float4-slot 0..15
      int slot = (c >> 1) ^ (rl & 7), half = c & 1;
      *reinterpret_cast<ushort4*>(&As[rl * 64 + slot * 8 + half * 4]) = f4_to_b4(pf[u]);
    }
    if (tl < 7) {                  // issue next tile's loads; hide under compute
      const float4* src = reinterpret_cast<const float4*>(eb + (tl + 1) * 8192);
      #pragma unroll
      for (int u = 0; u < 8; ++u) pf[u] = src[t + 256 * u];
    }
    __syncthreads();               // stage visible

    // wave w owns stage rows [w*32, w*32+32): 2 sub-tiles of 16 m
    #pragma unroll
    for (int sub = 0; sub < 2; ++sub) {
      int sr = w * 32 + sub * 16 + lr;      // A row in stage
      f4 acc = {};
      #pragma unroll
      for (int kk = 0; kk < 2; ++kk) {
        bf8 af = *reinterpret_cast<const bf8*>(&As[sr * 64 + (((kk * 4 + kg) ^ (sr & 7)) << 3)]);
        acc = __builtin_amdgcn_mfma_f32_16x16x32_bf16(af, bq[kk], acc, 0, 0, 0);
      }
      if (lr < 8) {                         // D: col=l&15 (=h), row=4*kg+rr
        int mbase = tl * 128 + w * 32 + sub * 16 + kg * 4;
        #pragma unroll
        for (int rr = 0; rr < 4; ++rr)
          lg[(mbase + rr) * 9 + lr] = acc[rr];
      }
    }
  }
  __syncthreads();                 // lg complete

  // ---- softmax: thread owns m = t + 256j; add node logits ----
  float l[4][8];
  #pragma unroll
  for (int j = 0; j < 4; ++j) {
    int m = t + 256 * j;
    #pragma unroll
    for (int h = 0; h < 8; ++h)
      l[j][h] = lg[m * 9 + h] + logN[((size_t)(b * 8 + h) * 1024 + n) * 1024 + m];
  }
  float mx[8], sm[8];
  #pragma unroll
  for (int h = 0; h < 8; ++h) {
    float v = fmaxf(fmaxf(l[0][h], l[1][h]), fmaxf(l[2][h], l[3][h]));
    #pragma unroll
    for (int off = 32; off; off >>= 1) v = fmaxf(v, __shfl_xor(v, off));
    if (lane == 0) red[0][w][h] = v;
  }
  __syncthreads();
  #pragma unroll
  for (int h = 0; h < 8; ++h)
    mx[h] = fmaxf(fmaxf(red[0][0][h], red[0][1][h]), fmaxf(red[0][2][h], red[0][3][h]));
  #pragma unroll
  for (int j = 0; j < 4; ++j)
    #pragma unroll
    for (int h = 0; h < 8; ++h)
      l[j][h] = __expf(l[j][h] - mx[h]);
  #pragma unroll
  for (int h = 0; h < 8; ++h) {
    float v = l[0][h] + l[1][h] + l[2][h] + l[3][h];
    #pragma unroll
    for (int off = 32; off; off >>= 1) v += __shfl_xor(v, off);
    if (lane == 0) red[1][w][h] = v;
  }
  __syncthreads();
  #pragma unroll
  for (int h = 0; h < 8; ++h)
    sm[h] = 1.0f / (red[1][0][h] + red[1][1][h] + red[1][2][h] + red[1][3][h]);
  #pragma unroll
  for (int h = 0; h < 8; ++h) {
    size_t base = ((size_t)(b * 8 + h) * 1024 + n) * 1024;
    #pragma unroll
    for (int j = 0; j < 4; ++j)
      attn[base + t + 256 * j] = f2b(l[j][h] * sm[h]);
  }
}

// ---------------- residual + layernorm (D=256, one block per row) ----------------
__global__ void k_ln(const float* __restrict__ a, const float* __restrict__ bb,
                     const float* __restrict__ g, const float* __restrict__ be,
                     float* __restrict__ of, ushort* __restrict__ ob) {
  int r = blockIdx.x, i = threadIdx.x;
  float t = a[(size_t)r * 256 + i] + bb[(size_t)r * 256 + i];
  __shared__ float red[4];

  float s = t;
  for (int off = 32; off; off >>= 1) s += __shfl_xor(s, off);
  if ((i & 63) == 0) red[i >> 6] = s;
  __syncthreads();
  float mean = (red[0] + red[1] + red[2] + red[3]) * (1.0f / 256.0f);
  __syncthreads();

  float d = t - mean;
  float q = d * d;
  for (int off = 32; off; off >>= 1) q += __shfl_xor(q, off);
  if ((i & 63) == 0) red[i >> 6] = q;
  __syncthreads();
  float var = (red[0] + red[1] + red[2] + red[3]) * (1.0f / 256.0f);

  float y = d * rsqrtf(var + 1e-6f) * g[i] + be[i];
  of[(size_t)r * 256 + i] = y;
  if (ob) ob[(size_t)r * 256 + i] = f2b(y);
}

// ---------------- launch ----------------

extern "C" void kernel_launch(void* const* d_in, const int* in_sizes, int n_in,
                              void* d_out, int out_size, void* d_ws, size_t ws_size,
                              hipStream_t stream) {
  (void)in_sizes; (void)n_in; (void)out_size; (void)ws_size;
  const float* node = (const float*)d_in[0];
  const float* edge = (const float*)d_in[1];
  const float* Wq   = (const float*)d_in[2];
  const float* Wk   = (const float*)d_in[3];
  const float* Wv   = (const float*)d_in[4];
  const float* Wp   = (const float*)d_in[5];
  const float* bp   = (const float*)d_in[6];
  const float* g1   = (const float*)d_in[7];
  const float* be1  = (const float*)d_in[8];
  const float* W1   = (const float*)d_in[9];
  const float* b1   = (const float*)d_in[10];
  const float* W2   = (const float*)d_in[11];
  const float* b2   = (const float*)d_in[12];
  const float* g2   = (const float*)d_in[13];
  const float* be2  = (const float*)d_in[14];
  float* out = (float*)d_out;

  char* ws = (char*)d_ws;
  size_t off = 0;
  auto alloc = [&](size_t bytes) -> char* {
    char* p = ws + off;
    off = (off + bytes + 255) & ~(size_t)255;
    return p;
  };
  ushort* node_bf = (ushort*)alloc((size_t)R_ * D_ * 2);
  ushort* wqkv    = (ushort*)alloc((size_t)256 * 1536 * 2);
  ushort* wke     = (ushort*)alloc((size_t)512 * 512 * 2);
  ushort* wp      = (ushort*)alloc((size_t)512 * 256 * 2);
  ushort* w1      = (ushort*)alloc((size_t)256 * 1024 * 2);
  ushort* w2      = (ushort*)alloc((size_t)1024 * 256 * 2);
  ushort* qkv     = (ushort*)alloc((size_t)R_ * 1536 * 2);
  float*  qe      = (float*) alloc((size_t)R_ * 512 * 4);
  ushort* knt     = (ushort*)alloc((size_t)16 * 64 * 1024 * 2);
  float*  logits  = (float*) alloc((size_t)16 * 1024 * 1024 * 4); // node logits, fp32
  ushort* attn    = (ushort*)alloc((size_t)16 * 1024 * 1024 * 2);
  ushort* mo      = (ushort*)alloc((size_t)R_ * 512 * 2);
  float*  mha     = (float*) alloc((size_t)R_ * 256 * 4);
  float*  xf      = (float*) alloc((size_t)R_ * 256 * 4);
  ushort* xb      = (ushort*)alloc((size_t)R_ * 256 * 2);
  ushort* hb      = (ushort*)alloc((size_t)R_ * 1024 * 2);
  float*  ff      = (float*) alloc((size_t)R_ * 256 * 4);

  // --- pack / convert ---
  k_cvt<<<dim3((R_ * D_ + 255) / 256), dim3(256), 0, stream>>>(node, node_bf, R_ * D_);
  k_cvt<<<dim3((512 * 256 + 255) / 256), dim3(256), 0, stream>>>(Wp, wp, 512 * 256);
  k_cvt<<<dim3((256 * 1024 + 255) / 256), dim3(256), 0, stream>>>(W1, w1, 256 * 1024);
  k_cvt<<<dim3((1024 * 256 + 255) / 256), dim3(256), 0, stream>>>(W2, w2, 1024 * 256);
  k_pack_wqkv<<<dim3(1536), dim3(256), 0, stream>>>(Wq, Wk, Wv, wqkv);
  k_pack_wke<<<dim3(1024), dim3(256), 0, stream>>>(Wk, wke);

  // --- qkv = node @ Wqkv (bf16 out, q pre-scaled) ---
  k_gemm<0, 1><<<dim3(32, 24, 1), dim3(256), 0, stream>>>(
      node_bf, wqkv, qkv, nullptr, 2048, 1536, 256, 256, 1536, 1536,
      0LL, 0LL, 0LL, 0LL, 0LL, 0LL);

  // --- qe = q @ blockdiag(WkE^T)  (fp32 out) ---
  k_gemm<0, 0><<<dim3(32, 8, 1), dim3(256), 0, stream>>>(
      qkv, wke, qe, nullptr, 2048, 512, 512, 1536, 512, 512,
      0LL, 0LL, 0LL, 0LL, 0LL, 0LL);

  // --- knT pack ---
  k_knT<<<dim3(4096), dim3(256), 0, stream>>>(qkv, knt);

  // --- node logits = q @ knT  (batched over (b,h), WRITE fp32) ---
  k_gemm<0, 0><<<dim3(16, 16, 16), dim3(256), 0, stream>>>(
      qkv, knt, logits, nullptr, 1024, 1024, 64, 1536, 1024, 1024,
      1572864LL, 64LL, 524288LL, 65536LL, 8388608LL, 1048576LL);

  // --- fused: edge MFMA dot + node logits + softmax -> bf16 attn ---
  k_fused<<<dim3(2048), dim3(256), 0, stream>>>(edge, qe, logits, attn);

  // --- mo = attn @ v  (batched, bf16 out, written as [b][n][h*64+o]) ---
  k_gemm<0, 1><<<dim3(16, 1, 16), dim3(256), 0, stream>>>(
      attn, qkv + 1024, mo, nullptr, 1024, 64, 1024, 1024, 1536, 512,
      8388608LL, 1048576LL, 1572864LL, 64LL, 524288LL, 64LL);

  // --- mha = mo @ Wp + bp  (fp32) ---
  k_gemm<2, 0><<<dim3(32, 4, 1), dim3(256), 0, stream>>>(
      mo, wp, mha, bp, 2048, 256, 512, 512, 256, 256,
      0LL, 0LL, 0LL, 0LL, 0LL, 0LL);

  // --- x = LN1(node + mha) -> xf (fp32), xb (bf16) ---
  k_ln<<<dim3(2048), dim3(256), 0, stream>>>(node, mha, g1, be1, xf, xb);

  // --- ffn hidden = relu(x @ W1 + b1)  (bf16) ---
  k_gemm<3, 1><<<dim3(32, 16, 1), dim3(256), 0, stream>>>(
      xb, w1, hb, b1, 2048, 1024, 256, 256, 1024, 1024,
      0LL, 0LL, 0LL, 0LL, 0LL, 0LL);

  // --- ff = hidden @ W2 + b2  (fp32) ---
  k_gemm<2, 0><<<dim3(32, 4, 1), dim3(256), 0, stream>>>(
      hb, w2, ff, b2, 2048, 256, 1024, 1024, 256, 256,
      0LL, 0LL, 0LL, 0LL, 0LL, 0LL);

  // --- out = LN2(x + ff)  (fp32 to d_out) ---
  k_ln<<<dim3(2048), dim3(256), 0, stream>>>(xf, ff, g2, be2, out, nullptr);
}

// Round 5
// 231.569 us; speedup vs baseline: 3.1412x; 1.2261x over previous
//
#include <hip/hip_runtime.h>
#include <hip/hip_bf16.h>
#include <hip/hip_fp16.h>

// Problem constants
#define B_  2
#define N_  1024
#define D_  256
#define E_  64
#define H_  8
#define HS_ 64
#define FF_ 1024
#define R_  (B_*N_)   // 2048 rows (b,n)

typedef short bf8 __attribute__((ext_vector_type(8)));   // 8 bf16 (bit pattern) = 4 VGPRs
typedef float f4  __attribute__((ext_vector_type(4)));

static __device__ __forceinline__ ushort f2b(float f) {
  __hip_bfloat16 h = __float2bfloat16(f);
  return *reinterpret_cast<ushort*>(&h);
}

static __device__ __forceinline__ ushort4 f4_to_b4(float4 v) {
  ushort4 r;
  r.x = f2b(v.x); r.y = f2b(v.y); r.z = f2b(v.z); r.w = f2b(v.w);
  return r;
}

// ---------------- fused weight pack (all bf16, B-matrices TRANSPOSED [N][K]) ----------------
// regions (elements): node_bf 524288 | wqkvT 393216 | wkeT 262144 | wpT 131072 | w1T 262144 | w2T 262144
__global__ void k_pack(const float* __restrict__ node, const float* __restrict__ Wq,
                       const float* __restrict__ Wk, const float* __restrict__ Wv,
                       const float* __restrict__ Wp, const float* __restrict__ W1,
                       const float* __restrict__ W2,
                       ushort* __restrict__ node_bf, ushort* __restrict__ wqkvT,
                       ushort* __restrict__ wkeT, ushort* __restrict__ wpT,
                       ushort* __restrict__ w1T, ushort* __restrict__ w2T) {
  int idx = blockIdx.x * 256 + threadIdx.x;
  if (idx < 524288) {                       // node -> bf16
    node_bf[idx] = f2b(node[idx]);
    return;
  }
  idx -= 524288;
  if (idx < 393216) {                       // wqkvT[c][i], c in [0,1536), K=256
    int c = idx >> 8, i = idx & 255;
    int mat = c >> 9, h = (c >> 6) & 7, o = c & 63;
    float v;
    if (mat == 0)      v = Wq[(h * 256 + i) * 64 + o] * 0.125f;   // q scaled 1/sqrt(HS)
    else if (mat == 1) v = Wk[(h * 320 + i) * 64 + o];            // Wk: [H][320][64]
    else               v = Wv[(h * 256 + i) * 64 + o];
    wqkvT[idx] = f2b(v);
    return;
  }
  idx -= 393216;
  if (idx < 262144) {                       // wkeT[c=h2*64+e][r=h*64+o]
    int c = idx >> 9, r = idx & 511;
    int h2 = c >> 6, e = c & 63, h = r >> 6, o = r & 63;
    wkeT[idx] = (h2 == h) ? f2b(Wk[(h * 320 + 256 + e) * 64 + o]) : (ushort)0;
    return;
  }
  idx -= 262144;
  if (idx < 131072) {                       // wpT[c][r], c in [0,256), r = h*64+i
    int c = idx >> 9, r = idx & 511;
    wpT[idx] = f2b(Wp[r * 256 + c]);
    return;
  }
  idx -= 131072;
  if (idx < 262144) {                       // w1T[c][k], c in [0,1024), K=256
    int c = idx >> 8, k = idx & 255;
    w1T[idx] = f2b(W1[k * 1024 + c]);
    return;
  }
  idx -= 262144;
  {                                         // w2T[c][k], c in [0,256), K=1024
    int c = idx >> 10, k = idx & 1023;
    w2T[idx] = f2b(W2[k * 256 + c]);
  }
}

// vT[b][h][o][m] <- qkv[(b*1024+m)*1536 + 1024 + h*64 + o]   (B^T panel for attn@v)
__global__ void k_vT(const ushort* __restrict__ qkv, ushort* __restrict__ vt) {
  int idx = blockIdx.x * 256 + threadIdx.x;   // 16*64*1024
  if (idx >= 16 * 64 * 1024) return;
  int m = idx & 1023;
  int rest = idx >> 10;
  int o = rest & 63;
  int bh = rest >> 6;
  int b = bh >> 3, h = bh & 7;
  vt[idx] = qkv[(size_t)(b * 1024 + m) * 1536 + 1024 + h * 64 + o];
}

// ---------------- generic bf16 MFMA GEMM, B pre-transposed ----------------
// C[M x N] = A[M x K] @ B[K x N];  Bt is B^T, row-major [N][K] with stride ldbt.
// EPI: 0=none, 2=+bias, 3=+bias,relu   OFMT: 0=f32, 1=bf16, 2=f16
// Batched via blockIdx.z: offset = (z>>3)*s1 + (z&7)*s2  (element offsets)
template<int EPI, int OFMT>
__global__ void k_gemm(const ushort* __restrict__ A, const ushort* __restrict__ Bt,
                       void* __restrict__ Cv, const float* __restrict__ bias,
                       int M, int N, int K, int lda, int ldbt, int ldc,
                       long long as1, long long as2, long long bs1, long long bs2,
                       long long cs1, long long cs2) {
  int z = blockIdx.z;
  const ushort* Ab = A  + (size_t)((z >> 3) * as1 + (z & 7) * as2);
  const ushort* Bb = Bt + (size_t)((z >> 3) * bs1 + (z & 7) * bs2);
  size_t coff = (size_t)((z >> 3) * cs1 + (z & 7) * cs2);
  int r0 = blockIdx.x * 64, c0 = blockIdx.y * 64;

  __shared__ ushort As[64][40];   // [row][k], +8 pad
  __shared__ ushort Bs[64][40];   // [col][k], +8 pad

  int tid = threadIdx.x;
  int lane = tid & 63, w = tid >> 6;
  int wm = w >> 1, wn = w & 1;            // wave -> 32x32 quadrant
  int kg = lane >> 4, lr = lane & 15;

  f4 acc[2][2] = {};

  for (int k0 = 0; k0 < K; k0 += 32) {
    __syncthreads();
    { // stage A tile 64x32 (one 16B load per thread)
      int row = tid >> 2, ch = tid & 3;
      *(int4*)&As[row][ch * 8] = *(const int4*)(Ab + (size_t)(r0 + row) * lda + k0 + ch * 8);
    }
    { // stage Bt tile 64x32 (same shape)
      int row = tid >> 2, ch = tid & 3;
      *(int4*)&Bs[row][ch * 8] = *(const int4*)(Bb + (size_t)(c0 + row) * ldbt + k0 + ch * 8);
    }
    __syncthreads();

    bf8 bfr[2];
    #pragma unroll
    for (int cb = 0; cb < 2; ++cb)
      bfr[cb] = *(const bf8*)&Bs[wn * 32 + cb * 16 + lr][kg * 8];    // B: col=l&15, k=8*kg+j
    #pragma unroll
    for (int rb = 0; rb < 2; ++rb) {
      bf8 af = *(const bf8*)&As[wm * 32 + rb * 16 + lr][kg * 8];     // A: row=l&15, k=8*kg+j
      #pragma unroll
      for (int cb = 0; cb < 2; ++cb)
        acc[rb][cb] = __builtin_amdgcn_mfma_f32_16x16x32_bf16(af, bfr[cb], acc[rb][cb], 0, 0, 0);
    }
  }

  float*  Cf = (float*)Cv;
  ushort* Cb = (ushort*)Cv;
  __half* Ch = (__half*)Cv;
  #pragma unroll
  for (int rb = 0; rb < 2; ++rb) {
    #pragma unroll
    for (int cb = 0; cb < 2; ++cb) {
      #pragma unroll
      for (int rr = 0; rr < 4; ++rr) {
        int row = r0 + wm * 32 + rb * 16 + kg * 4 + rr;   // D: col=l&15, row=4*kg+reg
        int col = c0 + wn * 32 + cb * 16 + lr;
        size_t ci = coff + (size_t)row * ldc + col;
        float v = acc[rb][cb][rr];
        if (EPI >= 2) v += bias[col];
        if (EPI == 3) v = fmaxf(v, 0.0f);
        if (OFMT == 1)      Cb[ci] = f2b(v);
        else if (OFMT == 2) Ch[ci] = __float2half(v);
        else                Cf[ci] = v;
      }
    }
  }
}

// ---------------- fused edge-logits (MFMA) + node-logits + softmax -> bf16 attn ----------------
// Per block (b,n): stream edge[b,n,:,:] (256 KB fp32) once; cvt to bf16 into a
// swizzled LDS tile; lgE[m,h] = edge_tile @ qe^T via mfma_16x16x32 (B-frags in regs);
// logits to LDS lg[1024][9] (fp16); add fp16 node logits; softmax; bf16 attn.
__global__ __launch_bounds__(256, 4) void k_fused(
    const float* __restrict__ edge, const float* __restrict__ qe,
    const __half* __restrict__ logN, ushort* __restrict__ attn) {
  int bid = blockIdx.x;            // b*1024 + n
  int b = bid >> 10, n = bid & 1023;
  int t = threadIdx.x;
  int lane = t & 63, w = t >> 6;
  int kg = lane >> 4, lr = lane & 15;

  __shared__ ushort As[128 * 64];  // 16 KB bf16 stage, slot^(row&7) swizzle
  __shared__ __half lg[1024 * 9];  // block logits [m][h], pad-9, fp16 (18 KB)
  __shared__ float red[2][4][8];

  // ---- B fragments (qe row -> bf16), built once, kept in 8 VGPRs ----
  bf8 bq[2];
  {
    const float* qrow = qe + (size_t)bid * 512 + (size_t)(lr & 7) * 64;
    #pragma unroll
    for (int kk = 0; kk < 2; ++kk) {
      float4 a  = *reinterpret_cast<const float4*>(&qrow[kk * 32 + kg * 8]);
      float4 c4 = *reinterpret_cast<const float4*>(&qrow[kk * 32 + kg * 8 + 4]);
      bq[kk][0] = (short)f2b(a.x);  bq[kk][1] = (short)f2b(a.y);
      bq[kk][2] = (short)f2b(a.z);  bq[kk][3] = (short)f2b(a.w);
      bq[kk][4] = (short)f2b(c4.x); bq[kk][5] = (short)f2b(c4.y);
      bq[kk][6] = (short)f2b(c4.z); bq[kk][7] = (short)f2b(c4.w);
    }
  }

  const float* eb = edge + (size_t)bid * 65536;   // 1024 rows x 64 floats

  // prefetch tile 0 (8 float4/thread, fully coalesced)
  float4 pf[8];
  #pragma unroll
  for (int u = 0; u < 8; ++u)
    pf[u] = reinterpret_cast<const float4*>(eb)[t + 256 * u];

  #pragma unroll 1
  for (int tl = 0; tl < 8; ++tl) {
    __syncthreads();               // prev tile's A-frag reads done
    #pragma unroll
    for (int u = 0; u < 8; ++u) {  // cvt fp32->bf16, swizzled write: slot ^= row&7
      int g = t + 256 * u;
      int rl = g >> 4, c = t & 15;          // row 0..127, float4-slot 0..15
      int slot = (c >> 1) ^ (rl & 7), half = c & 1;
      *reinterpret_cast<ushort4*>(&As[rl * 64 + slot * 8 + half * 4]) = f4_to_b4(pf[u]);
    }
    if (tl < 7) {                  // issue next tile's loads; hide under compute
      const float4* src = reinterpret_cast<const float4*>(eb + (tl + 1) * 8192);
      #pragma unroll
      for (int u = 0; u < 8; ++u) pf[u] = src[t + 256 * u];
    }
    __syncthreads();               // stage visible

    // wave w owns stage rows [w*32, w*32+32): 2 sub-tiles of 16 m
    #pragma unroll
    for (int sub = 0; sub < 2; ++sub) {
      int sr = w * 32 + sub * 16 + lr;      // A row in stage
      f4 acc = {};
      #pragma unroll
      for (int kk = 0; kk < 2; ++kk) {
        bf8 af = *reinterpret_cast<const bf8*>(&As[sr * 64 + (((kk * 4 + kg) ^ (sr & 7)) << 3)]);
        acc = __builtin_amdgcn_mfma_f32_16x16x32_bf16(af, bq[kk], acc, 0, 0, 0);
      }
      if (lr < 8) {                         // D: col=l&15 (=h), row=4*kg+rr
        int mbase = tl * 128 + w * 32 + sub * 16 + kg * 4;
        #pragma unroll
        for (int rr = 0; rr < 4; ++rr)
          lg[(mbase + rr) * 9 + lr] = __float2half(acc[rr]);
      }
    }
  }
  __syncthreads();                 // lg complete

  // ---- softmax: thread owns m = t + 256j; add node logits ----
  float l[4][8];
  #pragma unroll
  for (int j = 0; j < 4; ++j) {
    int m = t + 256 * j;
    #pragma unroll
    for (int h = 0; h < 8; ++h)
      l[j][h] = __half2float(lg[m * 9 + h]) +
                __half2float(logN[((size_t)(b * 8 + h) * 1024 + n) * 1024 + m]);
  }
  float mx[8], sm[8];
  #pragma unroll
  for (int h = 0; h < 8; ++h) {
    float v = fmaxf(fmaxf(l[0][h], l[1][h]), fmaxf(l[2][h], l[3][h]));
    #pragma unroll
    for (int off = 32; off; off >>= 1) v = fmaxf(v, __shfl_xor(v, off));
    if (lane == 0) red[0][w][h] = v;
  }
  __syncthreads();
  #pragma unroll
  for (int h = 0; h < 8; ++h)
    mx[h] = fmaxf(fmaxf(red[0][0][h], red[0][1][h]), fmaxf(red[0][2][h], red[0][3][h]));
  #pragma unroll
  for (int j = 0; j < 4; ++j)
    #pragma unroll
    for (int h = 0; h < 8; ++h)
      l[j][h] = __expf(l[j][h] - mx[h]);
  #pragma unroll
  for (int h = 0; h < 8; ++h) {
    float v = l[0][h] + l[1][h] + l[2][h] + l[3][h];
    #pragma unroll
    for (int off = 32; off; off >>= 1) v += __shfl_xor(v, off);
    if (lane == 0) red[1][w][h] = v;
  }
  __syncthreads();
  #pragma unroll
  for (int h = 0; h < 8; ++h)
    sm[h] = 1.0f / (red[1][0][h] + red[1][1][h] + red[1][2][h] + red[1][3][h]);
  #pragma unroll
  for (int h = 0; h < 8; ++h) {
    size_t base = ((size_t)(b * 8 + h) * 1024 + n) * 1024;
    #pragma unroll
    for (int j = 0; j < 4; ++j)
      attn[base + t + 256 * j] = f2b(l[j][h] * sm[h]);
  }
}

// ---------------- residual + layernorm (D=256, one block per row) ----------------
__global__ void k_ln(const float* __restrict__ a, const float* __restrict__ bb,
                     const float* __restrict__ g, const float* __restrict__ be,
                     float* __restrict__ of, ushort* __restrict__ ob) {
  int r = blockIdx.x, i = threadIdx.x;
  float t = a[(size_t)r * 256 + i] + bb[(size_t)r * 256 + i];
  __shared__ float red[4];

  float s = t;
  for (int off = 32; off; off >>= 1) s += __shfl_xor(s, off);
  if ((i & 63) == 0) red[i >> 6] = s;
  __syncthreads();
  float mean = (red[0] + red[1] + red[2] + red[3]) * (1.0f / 256.0f);
  __syncthreads();

  float d = t - mean;
  float q = d * d;
  for (int off = 32; off; off >>= 1) q += __shfl_xor(q, off);
  if ((i & 63) == 0) red[i >> 6] = q;
  __syncthreads();
  float var = (red[0] + red[1] + red[2] + red[3]) * (1.0f / 256.0f);

  float y = d * rsqrtf(var + 1e-6f) * g[i] + be[i];
  of[(size_t)r * 256 + i] = y;
  if (ob) ob[(size_t)r * 256 + i] = f2b(y);
}

// ---------------- launch ----------------

extern "C" void kernel_launch(void* const* d_in, const int* in_sizes, int n_in,
                              void* d_out, int out_size, void* d_ws, size_t ws_size,
                              hipStream_t stream) {
  (void)in_sizes; (void)n_in; (void)out_size; (void)ws_size;
  const float* node = (const float*)d_in[0];
  const float* edge = (const float*)d_in[1];
  const float* Wq   = (const float*)d_in[2];
  const float* Wk   = (const float*)d_in[3];
  const float* Wv   = (const float*)d_in[4];
  const float* Wp   = (const float*)d_in[5];
  const float* bp   = (const float*)d_in[6];
  const float* g1   = (const float*)d_in[7];
  const float* be1  = (const float*)d_in[8];
  const float* W1   = (const float*)d_in[9];
  const float* b1   = (const float*)d_in[10];
  const float* W2   = (const float*)d_in[11];
  const float* b2   = (const float*)d_in[12];
  const float* g2   = (const float*)d_in[13];
  const float* be2  = (const float*)d_in[14];
  float* out = (float*)d_out;

  char* ws = (char*)d_ws;
  size_t off = 0;
  auto alloc = [&](size_t bytes) -> char* {
    char* p = ws + off;
    off = (off + bytes + 255) & ~(size_t)255;
    return p;
  };
  ushort* node_bf = (ushort*)alloc((size_t)R_ * D_ * 2);          // 524288 el
  ushort* wqkvT   = (ushort*)alloc((size_t)1536 * 256 * 2);       // 393216 el
  ushort* wkeT    = (ushort*)alloc((size_t)512 * 512 * 2);        // 262144 el
  ushort* wpT     = (ushort*)alloc((size_t)256 * 512 * 2);        // 131072 el
  ushort* w1T     = (ushort*)alloc((size_t)1024 * 256 * 2);       // 262144 el
  ushort* w2T     = (ushort*)alloc((size_t)256 * 1024 * 2);       // 262144 el
  ushort* qkv     = (ushort*)alloc((size_t)R_ * 1536 * 2);        // 6 MiB
  float*  qe      = (float*) alloc((size_t)R_ * 512 * 4);         // 4 MiB
  ushort* vt      = (ushort*)alloc((size_t)16 * 64 * 1024 * 2);   // 2 MiB
  __half* logits  = (__half*)alloc((size_t)16 * 1024 * 1024 * 2); // 32 MiB fp16
  ushort* attn    = (ushort*)alloc((size_t)16 * 1024 * 1024 * 2); // 32 MiB
  ushort* mo      = (ushort*)alloc((size_t)R_ * 512 * 2);
  float*  mha     = (float*) alloc((size_t)R_ * 256 * 4);
  float*  xf      = (float*) alloc((size_t)R_ * 256 * 4);
  ushort* xb      = (ushort*)alloc((size_t)R_ * 256 * 2);
  ushort* hb      = (ushort*)alloc((size_t)R_ * 1024 * 2);
  float*  ff      = (float*) alloc((size_t)R_ * 256 * 4);

  // --- single fused pack (node + all weights, B-matrices transposed) ---
  k_pack<<<dim3(7168), dim3(256), 0, stream>>>(node, Wq, Wk, Wv, Wp, W1, W2,
                                               node_bf, wqkvT, wkeT, wpT, w1T, w2T);

  // --- qkv = node @ Wqkv (bf16 out, q pre-scaled) ---
  k_gemm<0, 1><<<dim3(32, 24, 1), dim3(256), 0, stream>>>(
      node_bf, wqkvT, qkv, nullptr, 2048, 1536, 256, 256, 256, 1536,
      0LL, 0LL, 0LL, 0LL, 0LL, 0LL);

  // --- qe = q @ blockdiag(WkE^T)  (fp32 out) ---
  k_gemm<0, 0><<<dim3(32, 8, 1), dim3(256), 0, stream>>>(
      qkv, wkeT, qe, nullptr, 2048, 512, 512, 1536, 512, 512,
      0LL, 0LL, 0LL, 0LL, 0LL, 0LL);

  // --- vT pack (for attn@v B-panel) ---
  k_vT<<<dim3(4096), dim3(256), 0, stream>>>(qkv, vt);

  // --- node logits = q @ kn^T  (batched over (b,h); Bt = kn slice of qkv; fp16 out) ---
  k_gemm<0, 2><<<dim3(16, 16, 16), dim3(256), 0, stream>>>(
      qkv, qkv + 512, logits, nullptr, 1024, 1024, 64, 1536, 1536, 1024,
      1572864LL, 64LL, 1572864LL, 64LL, 8388608LL, 1048576LL);

  // --- fused: edge MFMA dot + node logits + softmax -> bf16 attn ---
  k_fused<<<dim3(2048), dim3(256), 0, stream>>>(edge, qe, logits, attn);

  // --- mo = attn @ v  (batched; Bt = vT; bf16 out as [b][n][h*64+o]) ---
  k_gemm<0, 1><<<dim3(16, 1, 16), dim3(256), 0, stream>>>(
      attn, vt, mo, nullptr, 1024, 64, 1024, 1024, 1024, 512,
      8388608LL, 1048576LL, 524288LL, 65536LL, 524288LL, 64LL);

  // --- mha = mo @ Wp + bp  (fp32) ---
  k_gemm<2, 0><<<dim3(32, 4, 1), dim3(256), 0, stream>>>(
      mo, wpT, mha, bp, 2048, 256, 512, 512, 512, 256,
      0LL, 0LL, 0LL, 0LL, 0LL, 0LL);

  // --- x = LN1(node + mha) -> xf (fp32), xb (bf16) ---
  k_ln<<<dim3(2048), dim3(256), 0, stream>>>(node, mha, g1, be1, xf, xb);

  // --- ffn hidden = relu(x @ W1 + b1)  (bf16) ---
  k_gemm<3, 1><<<dim3(32, 16, 1), dim3(256), 0, stream>>>(
      xb, w1T, hb, b1, 2048, 1024, 256, 256, 256, 1024,
      0LL, 0LL, 0LL, 0LL, 0LL, 0LL);

  // --- ff = hidden @ W2 + b2  (fp32) ---
  k_gemm<2, 0><<<dim3(32, 4, 1), dim3(256), 0, stream>>>(
      hb, w2T, ff, b2, 2048, 256, 1024, 1024, 1024, 256,
      0LL, 0LL, 0LL, 0LL, 0LL, 0LL);

  // --- out = LN2(x + ff)  (fp32 to d_out) ---
  k_ln<<<dim3(2048), dim3(256), 0, stream>>>(xf, ff, g2, be2, out, nullptr);
}